// Round 11
// baseline (328.511 us; speedup 1.0000x reference)
//
#include <hip/hip_runtime.h>

typedef unsigned short u16;
typedef unsigned long long u64;
typedef __attribute__((ext_vector_type(8))) short bf16x8;
typedef __attribute__((ext_vector_type(4))) float f32x4;

__device__ inline u16 f2bf(float f) {
  unsigned int u = __float_as_uint(f);
  u += 0x7fffu + ((u >> 16) & 1u);
  return (u16)(u >> 16);
}
__device__ inline float bf2f(u16 h) { return __uint_as_float(((unsigned int)h) << 16); }

__device__ inline void gload_lds16(const void* gp, void* lp) {
  __builtin_amdgcn_global_load_lds(
      (const __attribute__((address_space(1))) unsigned int*)gp,
      (__attribute__((address_space(3))) unsigned int*)lp, 16, 0, 0);
}

// ---------------- LayerNorm: f32 [rows][1024] -> bf16 ----------------
__global__ __launch_bounds__(256) void ln_kernel(const float* __restrict__ x,
                                                 const float* __restrict__ g,
                                                 const float* __restrict__ beta,
                                                 u16* __restrict__ y) {
  __shared__ float red[8];
  const int row = blockIdx.x;
  const int t = threadIdx.x;
  const float4 xv = *(const float4*)(x + (long)row * 1024 + t * 4);
  float s = xv.x + xv.y + xv.z + xv.w;
  float sq = xv.x * xv.x + xv.y * xv.y + xv.z * xv.z + xv.w * xv.w;
#pragma unroll
  for (int d = 1; d < 64; d <<= 1) {
    s += __shfl_xor(s, d);
    sq += __shfl_xor(sq, d);
  }
  if ((t & 63) == 0) { red[t >> 6] = s; red[4 + (t >> 6)] = sq; }
  __syncthreads();
  s = red[0] + red[1] + red[2] + red[3];
  sq = red[4] + red[5] + red[6] + red[7];
  const float mean = s * (1.f / 1024.f);
  const float var = sq * (1.f / 1024.f) - mean * mean;
  const float inv = rsqrtf(var + 1e-5f);
  float xe[4] = {xv.x, xv.y, xv.z, xv.w};
  u16 ov[4];
#pragma unroll
  for (int e = 0; e < 4; ++e)
    ov[e] = f2bf((xe[e] - mean) * inv * g[t * 4 + e] + beta[t * 4 + e]);
  *(u64*)(y + (long)row * 1024 + t * 4) = *(u64*)ov;
}

// ------------- transpose + convert: f32 in[R][C] -> bf16 out[C][R] -------------
__global__ __launch_bounds__(256) void transpose_bf16(const float* __restrict__ in,
                                                      u16* __restrict__ out,
                                                      int R, int C) {
  __shared__ float tile[64][33];
  const int t = threadIdx.x;
  const int tx = t & 31, ty = t >> 5;
  const int rx = t & 63, cy = t >> 6;
  const long r0 = (long)blockIdx.y * 64, c0 = (long)blockIdx.x * 32;
#pragma unroll
  for (int i = 0; i < 8; ++i)
    tile[ty + i * 8][tx] = in[(r0 + ty + i * 8) * C + c0 + tx];
  __syncthreads();
#pragma unroll
  for (int i = 0; i < 8; ++i)
    out[(c0 + i * 4 + cy) * R + r0 + rx] = f2bf(tile[rx][i * 4 + cy]);
}

// ---- interleaved transpose for gate/up: col c -> row (c>>4)*32 + off + (c&15) ----
__global__ __launch_bounds__(256) void transpose_ilv(const float* __restrict__ in,
                                                     u16* __restrict__ out,
                                                     int R, int C, int off) {
  __shared__ float tile[64][33];
  const int t = threadIdx.x;
  const int tx = t & 31, ty = t >> 5;
  const int rx = t & 63, cy = t >> 6;
  const long r0 = (long)blockIdx.y * 64, c0 = (long)blockIdx.x * 32;
#pragma unroll
  for (int i = 0; i < 8; ++i)
    tile[ty + i * 8][tx] = in[(r0 + ty + i * 8) * C + c0 + tx];
  __syncthreads();
#pragma unroll
  for (int i = 0; i < 8; ++i) {
    const int c = (int)c0 + i * 4 + cy;
    const long v = ((long)(c >> 4) << 5) + off + (c & 15);
    out[v * R + r0 + rx] = f2bf(tile[rx][i * 4 + cy]);
  }
}

// ------------- RoPE cos/sin table: tbl[0..65535]=cos(s,d0), [65536..]=sin -------------
__global__ __launch_bounds__(256) void trig_kernel(float* __restrict__ tbl) {
  const int i = blockIdx.x * 256 + threadIdx.x;   // 65536 = 2048 s x 32 d0
  const int s = i >> 5, d0 = i & 31;
  const float inv = exp2f((float)d0 * (-13.287712379549449f / 32.f));
  float sn, cs;
  sincosf((float)s * inv, &sn, &cs);
  tbl[i] = cs;
  tbl[65536 + i] = sn;
}

// ------ prefill: out = x1 + bias (N=1024 bias) ------
__global__ __launch_bounds__(256) void prefill_add(const float* __restrict__ x1,
                                                   const float* __restrict__ bias,
                                                   float* __restrict__ out) {
  const long i = ((long)blockIdx.x * 256 + threadIdx.x) * 4;
  float4 v = *(const float4*)(x1 + i);
  const float4 bb = *(const float4*)(bias + (int)(i & 1023));
  v.x += bb.x; v.y += bb.y; v.z += bb.z; v.w += bb.w;
  *(float4*)(out + i) = v;
}

// ------------- local-causal flash attention, window 256, hd=64, H=16 -------------
__global__ __launch_bounds__(64, 4) void attn_kernel(const u16* __restrict__ qr,
                                                     const u16* __restrict__ kr,
                                                     const u16* __restrict__ vt,
                                                     u16* __restrict__ o) {
  __shared__ __attribute__((aligned(16))) u16 Pl[16][40];
  int wg = blockIdx.x;
  wg = (wg & 7) * 512 + (wg >> 3);
  const int qt = wg & 127;
  const int bh = wg >> 7;
  const int qs = qt * 16;
  const int l = threadIdx.x;
  const int lr = l & 15, lg = l >> 4;
  const long bho = (long)(bh >> 4) * 2048 * 1024 + (long)(bh & 15) * 64;
  const long vtb = (long)bh * 64 * 2048;

  const u16* qp = qr + bho + (long)(qs + lr) * 1024 + lg * 8;
  const bf16x8 aq0 = *(const bf16x8*)qp;
  const bf16x8 aq1 = *(const bf16x8*)(qp + 32);

  f32x4 oacc[4];
#pragma unroll
  for (int nt = 0; nt < 4; ++nt) { oacc[nt][0] = 0.f; oacc[nt][1] = 0.f; oacc[nt][2] = 0.f; oacc[nt][3] = 0.f; }
  float m_[4], ls[4];
#pragma unroll
  for (int r = 0; r < 4; ++r) { m_[r] = -1e30f; ls[r] = 0.f; }

  for (int ch = 0; ch < 9; ++ch) {
    const int j0 = qs - 256 + ch * 32;
    if (j0 + 32 <= 0) continue;

    const int jc0u = j0 + lr;
    const int jc1u = j0 + 16 + lr;
    const int jc0 = min(max(jc0u, 0), 2047);
    const int jc1 = min(max(jc1u, 0), 2047);
    const u16* kp0 = kr + bho + (long)jc0 * 1024 + lg * 8;
    const u16* kp1 = kr + bho + (long)jc1 * 1024 + lg * 8;
    const bf16x8 b00 = *(const bf16x8*)kp0;
    const bf16x8 b01 = *(const bf16x8*)(kp0 + 32);
    const bf16x8 b10 = *(const bf16x8*)kp1;
    const bf16x8 b11 = *(const bf16x8*)(kp1 + 32);

    f32x4 z; z[0] = 0.f; z[1] = 0.f; z[2] = 0.f; z[3] = 0.f;
    f32x4 s0 = __builtin_amdgcn_mfma_f32_16x16x32_bf16(aq0, b00, z, 0, 0, 0);
    s0 = __builtin_amdgcn_mfma_f32_16x16x32_bf16(aq1, b01, s0, 0, 0, 0);
    f32x4 s1 = __builtin_amdgcn_mfma_f32_16x16x32_bf16(aq0, b10, z, 0, 0, 0);
    s1 = __builtin_amdgcn_mfma_f32_16x16x32_bf16(aq1, b11, s1, 0, 0, 0);

    float p0[4], p1[4], al[4];
#pragma unroll
    for (int r = 0; r < 4; ++r) {
      const int qg = qs + lg * 4 + r;
      const bool v0 = (jc0u >= 0) & (jc0u <= qg) & (qg - jc0u <= 256);
      const bool v1 = (jc1u >= 0) & (jc1u <= qg) & (qg - jc1u <= 256);
      const float t0 = v0 ? s0[r] : -1e30f;
      const float t1 = v1 ? s1[r] : -1e30f;
      float mx = fmaxf(t0, t1);
      mx = fmaxf(mx, __shfl_xor(mx, 1));
      mx = fmaxf(mx, __shfl_xor(mx, 2));
      mx = fmaxf(mx, __shfl_xor(mx, 4));
      mx = fmaxf(mx, __shfl_xor(mx, 8));
      const float mn = fmaxf(m_[r], mx);
      if (mn < -1e29f) {
        al[r] = 1.f; p0[r] = 0.f; p1[r] = 0.f;
      } else {
        al[r] = __expf(m_[r] - mn);
        p0[r] = (t0 < -1e29f) ? 0.f : __expf(t0 - mn);
        p1[r] = (t1 < -1e29f) ? 0.f : __expf(t1 - mn);
      }
      m_[r] = mn;
      float rs = p0[r] + p1[r];
      rs += __shfl_xor(rs, 1);
      rs += __shfl_xor(rs, 2);
      rs += __shfl_xor(rs, 4);
      rs += __shfl_xor(rs, 8);
      ls[r] = ls[r] * al[r] + rs;
    }
#pragma unroll
    for (int r = 0; r < 4; ++r) {
      Pl[lg * 4 + r][lr] = f2bf(p0[r]);
      Pl[lg * 4 + r][lr + 16] = f2bf(p1[r]);
    }
    asm volatile("s_waitcnt lgkmcnt(0)" ::: "memory");
    const bf16x8 pa = *(const bf16x8*)(&Pl[lr][lg * 8]);

    const int jb = min(max(j0 + lg * 8, 0), 2040);
    const u16* vp = vt + vtb + (long)lr * 2048 + jb;
#pragma unroll
    for (int nt = 0; nt < 4; ++nt) {
      const bf16x8 bv = *(const bf16x8*)(vp + (long)(nt * 16) * 2048);
      f32x4 oa = oacc[nt];
#pragma unroll
      for (int r = 0; r < 4; ++r) oa[r] *= al[r];
      oacc[nt] = __builtin_amdgcn_mfma_f32_16x16x32_bf16(pa, bv, oa, 0, 0, 0);
    }
  }
#pragma unroll
  for (int nt = 0; nt < 4; ++nt)
#pragma unroll
    for (int r = 0; r < 4; ++r) {
      const long qg = qs + lg * 4 + r;
      o[bho + qg * 1024 + nt * 16 + lr] = f2bf(oacc[nt][r] / ls[r]);
    }
}

// ========== 256x256 8-phase GEMM, BK=64, A triple-buffered (160 KiB LDS) ==========
// Pipelined: 1 barrier/phase; A-frag reads issued one phase ahead (aA/aB reg dbuf);
// B frags read pre-tile. Read-before-overwrite safety: each wave's b/a reads
// complete (compiler lgkm wait) before its q0/q1 MFMAs, and B(t+2) staging is
// issued only after the q1-end barrier, which every wave reaches after its q0 MFMA.
// Block mapping: XCD-contiguous chunks + GROUP_M=8.
// EPI 6: qkv fused rope epilogue (Cb=qr, P1=kr, P2=vt[bh][64][2048], tbl=cos/sin)
// EPI 7: fused gate/up (interleaved wguT, virtual N=8192) -> bf16 [M][4096]
// EPI 8: atomic split-K: unsafeAtomicAdd into Cf0 (pre-filled with residual/bias)
__device__ __forceinline__ void stage_half(u16* lds, int ldsbase,
                                           const u16* gp, int ld, int col,
                                           int tid, int w) {
  const int r0 = tid >> 3;
  const int sw = ((tid & 7) ^ (r0 & 7)) << 3;
  gload_lds16(gp + (long)r0 * ld + col + sw, lds + ldsbase + w * 512);
  gload_lds16(gp + (long)(r0 + 64) * ld + col + sw, lds + ldsbase + 4096 + w * 512);
}

template <int EPI>
__global__ __launch_bounds__(512, 2) void gemm8p(const u16* __restrict__ A,
                                                 const u16* __restrict__ BT,
                                                 u16* __restrict__ Cb,
                                                 const float* __restrict__ bias,
                                                 float* __restrict__ Cf0,
                                                 u16* __restrict__ P1,
                                                 u16* __restrict__ P2,
                                                 const float* __restrict__ tbl,
                                                 int M, int N, int Kfull, int Kl) {
  __shared__ __attribute__((aligned(16))) u16 lds[81920];   // 160 KiB
  const int tid = threadIdx.x;
  const int w = tid >> 6, l = tid & 63;
  const int lr = l & 15, lg = l >> 4;
  const int l7 = l & 7;
  const int wr = w >> 2, wc = w & 3;
  const int nbx = N >> 8, nby = M >> 8;
  int wg = blockIdx.x;
  { const int cpx = gridDim.x >> 3; wg = (wg & 7) * cpx + (wg >> 3); }
  const int z = wg / (nbx * nby);
  const int rem = wg % (nbx * nby);
  const int rr = rem % (8 * nbx);
  const long m0 = (long)((rem / (8 * nbx)) * 8 + (rr & 7)) * 256;
  const long n0 = (long)(rr >> 3) * 256;
  const long koff = (long)z * Kl;
  const int NT = Kl >> 6;

  f32x4 acc[8][4];
#pragma unroll
  for (int i = 0; i < 8; ++i)
#pragma unroll
    for (int j = 0; j < 4; ++j) { acc[i][j][0] = 0.f; acc[i][j][1] = 0.f; acc[i][j][2] = 0.f; acc[i][j][3] = 0.f; }

  const u16* Alo = A + m0 * Kfull + koff;
  const u16* Ahi = A + (m0 + 128) * Kfull + koff;
  const u16* Blo = BT + n0 * Kfull + koff;
  const u16* Bhi = BT + (n0 + 128) * Kfull + koff;

  // prologue: A(0), B(0), A(1), B(1) — oldest-first so vmcnt(8) releases A0/B0
  stage_half(lds, 0, Alo, Kfull, 0, tid, w);
  stage_half(lds, 8192, Ahi, Kfull, 0, tid, w);
  stage_half(lds, 49152, Blo, Kfull, 0, tid, w);
  stage_half(lds, 57344, Bhi, Kfull, 0, tid, w);
  stage_half(lds, 16384, Alo, Kfull, 64, tid, w);
  stage_half(lds, 24576, Ahi, Kfull, 64, tid, w);
  stage_half(lds, 65536, Blo, Kfull, 64, tid, w);
  stage_half(lds, 73728, Bhi, Kfull, 64, tid, w);
  asm volatile("s_waitcnt vmcnt(8)" ::: "memory");
  __builtin_amdgcn_s_barrier();

  for (int t = 0; t < NT; ++t) {
    const int abuf = t % 3;
    int sA = abuf + 2; if (sA >= 3) sA -= 3;     // (t+2)%3
    const int p = t & 1;
    const int baA = abuf * 16384 + wr * 8192;
    const int bB = 49152 + p * 16384;
    bf16x8 aA[2][2], aB[2][2], b[4][2];
    // pre-tile reads: phase-0 A rows + all B
#pragma unroll
    for (int m2 = 0; m2 < 2; ++m2)
#pragma unroll
      for (int kh = 0; kh < 2; ++kh)
        aA[m2][kh] = *(const bf16x8*)(lds + baA + (m2 * 16 + lr) * 64 + (((kh * 4 + lg) ^ l7) << 3));
#pragma unroll
    for (int fn = 0; fn < 4; ++fn) {
      const int rb = wc * 64 + fn * 16 + lr;
#pragma unroll
      for (int kh = 0; kh < 2; ++kh)
        b[fn][kh] = *(const bf16x8*)(lds + bB + (rb >> 7) * 8192 + (rb & 127) * 64 + (((kh * 4 + lg) ^ l7) << 3));
    }
#pragma unroll
    for (int q = 0; q < 4; ++q) {
      // stage one half-tile of t+2 (A -> 3rd buffer; B -> same-parity buffer)
      if (t + 2 < NT) {
        if (q == 0) stage_half(lds, sA * 16384, Alo, Kfull, (t + 2) * 64, tid, w);
        if (q == 1) stage_half(lds, sA * 16384 + 8192, Ahi, Kfull, (t + 2) * 64, tid, w);
        if (q == 2) stage_half(lds, bB, Blo, Kfull, (t + 2) * 64, tid, w);
        if (q == 3) stage_half(lds, bB + 8192, Bhi, Kfull, (t + 2) * 64, tid, w);
      }
      __builtin_amdgcn_s_setprio(1);
#pragma unroll
      for (int m2 = 0; m2 < 2; ++m2)
#pragma unroll
        for (int fn = 0; fn < 4; ++fn)
#pragma unroll
          for (int kh = 0; kh < 2; ++kh)
            acc[q * 2 + m2][fn] = __builtin_amdgcn_mfma_f32_16x16x32_bf16(
                (q & 1) ? aB[m2][kh] : aA[m2][kh], b[fn][kh], acc[q * 2 + m2][fn], 0, 0, 0);
      __builtin_amdgcn_s_setprio(0);
      if (q < 3) {
        // prefetch next phase's A rows (buffer abuf is stable all tile)
#pragma unroll
        for (int m2 = 0; m2 < 2; ++m2)
#pragma unroll
          for (int kh = 0; kh < 2; ++kh) {
            const int rowA = ((q + 1) * 2 + m2) * 16 + lr;
            const bf16x8 v = *(const bf16x8*)(lds + baA + rowA * 64 + (((kh * 4 + lg) ^ l7) << 3));
            if (q & 1) aA[m2][kh] = v; else aB[m2][kh] = v;
          }
      }
      if (q == 3) {
        if (t + 2 < NT) { asm volatile("s_waitcnt vmcnt(8)" ::: "memory"); }
        else            { asm volatile("s_waitcnt vmcnt(0)" ::: "memory"); }
      }
      __builtin_amdgcn_s_barrier();
    }
  }

  if constexpr (EPI == 6) {
    const int regn = (int)((n0 + wc * 64) >> 10);   // 0=Q, 1=K, else V
    if (regn < 2) {
      const float scale = (regn == 0) ? 0.125f : 1.f;
      u16* dst = (regn == 0) ? Cb : P1;
      const int cbase = (int)(n0 & 1023) + wc * 64 + lr;
#pragma unroll
      for (int fm = 0; fm < 8; ++fm) {
        const long mr = m0 + wr * 128 + fm * 16 + lg * 4;
#pragma unroll
        for (int fn = 0; fn < 2; ++fn) {
          const int c1 = cbase + fn * 16;
          const int d0 = fn * 16 + lr;
#pragma unroll
          for (int r = 0; r < 4; ++r) {
            const long row = mr + r;
            const int s = (int)(row & 2047);
            const float cs = tbl[(s << 5) + d0];
            const float sn = tbl[65536 + (s << 5) + d0];
            const float x1v = acc[fm][fn][r], x2v = acc[fm][fn + 2][r];
            dst[row * 1024 + c1] = f2bf((x1v * cs - x2v * sn) * scale);
            dst[row * 1024 + c1 + 32] = f2bf((x2v * cs + x1v * sn) * scale);
          }
        }
      }
    } else {
#pragma unroll
      for (int fm = 0; fm < 8; ++fm) {
        const long mr = m0 + wr * 128 + fm * 16 + lg * 4;
        const int bb = (int)(mr >> 11);
        const int s = (int)(mr & 2047);
#pragma unroll
        for (int fn = 0; fn < 4; ++fn) {
          const int ncv = (int)(n0 - 2048) + wc * 64 + fn * 16 + lr;
          const int h = ncv >> 6, d = ncv & 63;
          u16 pk[4];
#pragma unroll
          for (int r = 0; r < 4; ++r) pk[r] = f2bf(acc[fm][fn][r]);
          *(u64*)(P2 + (long)(bb * 16 + h) * 131072 + (long)d * 2048 + s) = *(u64*)pk;
        }
      }
    }
    return;
  }

  if constexpr (EPI == 7) {
    const int rcb = (int)((n0 + wc * 64) >> 1);
#pragma unroll
    for (int fm = 0; fm < 8; ++fm) {
      const long mr = m0 + wr * 128 + fm * 16 + lg * 4;
#pragma unroll
      for (int fp = 0; fp < 2; ++fp) {
        const int rc = rcb + fp * 16 + lr;
        const float bg = bias[rc];
        const float bu = tbl[rc];
#pragma unroll
        for (int r = 0; r < 4; ++r) {
          const float g = acc[fm][2 * fp][r] + bg;
          const float u = acc[fm][2 * fp + 1][r] + bu;
          const float sg = 1.f / (1.f + __expf(-u));
          Cb[(mr + r) * 4096 + rc] = f2bf(g * u * sg);
        }
      }
    }
    return;
  }

  if constexpr (EPI == 8) {
    // atomic split-K: accumulate into pre-filled Cf0
#pragma unroll
    for (int fm = 0; fm < 8; ++fm) {
      const long mr = m0 + wr * 128 + fm * 16 + lg * 4;
#pragma unroll
      for (int fn = 0; fn < 4; ++fn) {
        const long nc = n0 + wc * 64 + fn * 16 + lr;
#pragma unroll
        for (int r = 0; r < 4; ++r)
          unsafeAtomicAdd(&Cf0[(mr + r) * N + nc], acc[fm][fn][r]);
      }
    }
    return;
  }
}

extern "C" void kernel_launch(void* const* d_in, const int* in_sizes, int n_in,
                              void* d_out, int out_size, void* d_ws, size_t ws_size,
                              hipStream_t stream) {
  (void)in_sizes; (void)n_in; (void)out_size; (void)ws_size;
  const float* x      = (const float*)d_in[0];
  const float* w_qkv  = (const float*)d_in[1];
  const float* w_out  = (const float*)d_in[2];
  const float* g1     = (const float*)d_in[3];
  const float* b1     = (const float*)d_in[4];
  const float* g2     = (const float*)d_in[5];
  const float* b2     = (const float*)d_in[6];
  const float* w_gate = (const float*)d_in[7];
  const float* b_gate = (const float*)d_in[8];
  const float* w_up   = (const float*)d_in[9];
  const float* b_up   = (const float*)d_in[10];
  const float* w_down = (const float*)d_in[11];
  const float* b_down = (const float*)d_in[12];
  float* out = (float*)d_out;

  // Workspace layout (MB), liveness-checked:
  //  0-8 wdownT | 8-16 y | 16-22 wqkvT | 22-24 woutT | 24-40 wguT
  //  40-48 qr | 48-56 kr | 56-64 vt | 64-64.5 trig (dead after qkv) | 64-72 o_
  //  72-88 x1 (prefilled from x; atomically accumulated by out-proj)
  //  88-120 gated (qr/kr/vt/o_ dead by MLP)
  const size_t MB = 1u << 20;
  char* ws = (char*)d_ws;
  u16*   wdownT = (u16*)(ws + 0 * MB);
  u16*   y      = (u16*)(ws + 8 * MB);
  u16*   wqkvT  = (u16*)(ws + 16 * MB);
  u16*   woutT  = (u16*)(ws + 22 * MB);
  u16*   wguT   = (u16*)(ws + 24 * MB);     // [8192][1024] interleaved gate/up
  u16*   qr_    = (u16*)(ws + 40 * MB);
  u16*   kr_    = (u16*)(ws + 48 * MB);
  u16*   vt     = (u16*)(ws + 56 * MB);
  float* trig   = (float*)(ws + 64 * MB);
  u16*   o_     = (u16*)(ws + 64 * MB);     // overwrites trig after qkv done
  float* x1     = (float*)(ws + 72 * MB);
  u16*   gated  = (u16*)(ws + 88 * MB);

  const dim3 blk(256);
  transpose_bf16<<<dim3(3072 / 32, 1024 / 64), blk, 0, stream>>>(w_qkv, wqkvT, 1024, 3072);
  transpose_bf16<<<dim3(1024 / 32, 1024 / 64), blk, 0, stream>>>(w_out, woutT, 1024, 1024);
  transpose_ilv<<<dim3(4096 / 32, 1024 / 64), blk, 0, stream>>>(w_gate, wguT, 1024, 4096, 0);
  transpose_ilv<<<dim3(4096 / 32, 1024 / 64), blk, 0, stream>>>(w_up, wguT, 1024, 4096, 16);
  transpose_bf16<<<dim3(1024 / 32, 4096 / 64), blk, 0, stream>>>(w_down, wdownT, 4096, 1024);
  trig_kernel<<<256, blk, 0, stream>>>(trig);

  // LN1: x -> y
  ln_kernel<<<4096, blk, 0, stream>>>(x, g1, b1, y);
  // QKV projection + fused RoPE/V-transpose epilogue -> qr, kr, vt
  gemm8p<6><<<dim3((3072 / 256) * (4096 / 256)), dim3(512), 0, stream>>>(
      y, wqkvT, qr_, nullptr, nullptr, kr_, vt, trig, 4096, 3072, 1024, 1024);
  // local-causal attention -> o_
  attn_kernel<<<4096, dim3(64), 0, stream>>>(qr_, kr_, vt, o_);
  // x1 = x (residual base), then out-proj atomically accumulates into it
  hipMemcpyAsync(x1, x, (size_t)4096 * 1024 * 4, hipMemcpyDeviceToDevice, stream);
  gemm8p<8><<<dim3(4 * 16 * 4), dim3(512), 0, stream>>>(
      o_, woutT, nullptr, nullptr, x1, nullptr, nullptr, nullptr,
      4096, 1024, 1024, 256);
  // LN2: x1 -> y
  ln_kernel<<<4096, blk, 0, stream>>>(x1, g2, b2, y);
  // fused gate/up dual GEMM (virtual N=8192, interleaved) -> gated bf16 [4096][4096]
  gemm8p<7><<<dim3((8192 / 256) * (4096 / 256)), dim3(512), 0, stream>>>(
      y, wguT, gated, b_gate, nullptr, nullptr, nullptr, b_up,
      4096, 8192, 1024, 1024);
  // out = x1 + b_down, then down-proj atomically accumulates into it
  prefill_add<<<4096, blk, 0, stream>>>(x1, b_down, out);
  gemm8p<8><<<dim3(4 * 16 * 4), dim3(512), 0, stream>>>(
      gated, wdownT, nullptr, nullptr, out, nullptr, nullptr, nullptr,
      4096, 1024, 4096, 1024);
}

// Round 12
// 265.922 us; speedup vs baseline: 1.2354x; 1.2354x over previous
//
#include <hip/hip_runtime.h>

typedef unsigned short u16;
typedef unsigned long long u64;
typedef __attribute__((ext_vector_type(8))) short bf16x8;
typedef __attribute__((ext_vector_type(4))) float f32x4;

__device__ inline u16 f2bf(float f) {
  unsigned int u = __float_as_uint(f);
  u += 0x7fffu + ((u >> 16) & 1u);
  return (u16)(u >> 16);
}
__device__ inline float bf2f(u16 h) { return __uint_as_float(((unsigned int)h) << 16); }

__device__ inline void gload_lds16(const void* gp, void* lp) {
  __builtin_amdgcn_global_load_lds(
      (const __attribute__((address_space(1))) unsigned int*)gp,
      (__attribute__((address_space(3))) unsigned int*)lp, 16, 0, 0);
}

// ---------------- LayerNorm: f32 [rows][1024] -> bf16 ----------------
__global__ __launch_bounds__(256) void ln_kernel(const float* __restrict__ x,
                                                 const float* __restrict__ g,
                                                 const float* __restrict__ beta,
                                                 u16* __restrict__ y) {
  __shared__ float red[8];
  const int row = blockIdx.x;
  const int t = threadIdx.x;
  const float4 xv = *(const float4*)(x + (long)row * 1024 + t * 4);
  float s = xv.x + xv.y + xv.z + xv.w;
  float sq = xv.x * xv.x + xv.y * xv.y + xv.z * xv.z + xv.w * xv.w;
#pragma unroll
  for (int d = 1; d < 64; d <<= 1) {
    s += __shfl_xor(s, d);
    sq += __shfl_xor(sq, d);
  }
  if ((t & 63) == 0) { red[t >> 6] = s; red[4 + (t >> 6)] = sq; }
  __syncthreads();
  s = red[0] + red[1] + red[2] + red[3];
  sq = red[4] + red[5] + red[6] + red[7];
  const float mean = s * (1.f / 1024.f);
  const float var = sq * (1.f / 1024.f) - mean * mean;
  const float inv = rsqrtf(var + 1e-5f);
  float xe[4] = {xv.x, xv.y, xv.z, xv.w};
  u16 ov[4];
#pragma unroll
  for (int e = 0; e < 4; ++e)
    ov[e] = f2bf((xe[e] - mean) * inv * g[t * 4 + e] + beta[t * 4 + e]);
  *(u64*)(y + (long)row * 1024 + t * 4) = *(u64*)ov;
}

// ------------- transpose + convert: f32 in[R][C] -> bf16 out[C][R] -------------
__global__ __launch_bounds__(256) void transpose_bf16(const float* __restrict__ in,
                                                      u16* __restrict__ out,
                                                      int R, int C) {
  __shared__ float tile[64][33];
  const int t = threadIdx.x;
  const int tx = t & 31, ty = t >> 5;
  const int rx = t & 63, cy = t >> 6;
  const long r0 = (long)blockIdx.y * 64, c0 = (long)blockIdx.x * 32;
#pragma unroll
  for (int i = 0; i < 8; ++i)
    tile[ty + i * 8][tx] = in[(r0 + ty + i * 8) * C + c0 + tx];
  __syncthreads();
#pragma unroll
  for (int i = 0; i < 8; ++i)
    out[(c0 + i * 4 + cy) * R + r0 + rx] = f2bf(tile[rx][i * 4 + cy]);
}

// ---- interleaved transpose for gate/up: col c -> row (c>>4)*32 + off + (c&15) ----
__global__ __launch_bounds__(256) void transpose_ilv(const float* __restrict__ in,
                                                     u16* __restrict__ out,
                                                     int R, int C, int off) {
  __shared__ float tile[64][33];
  const int t = threadIdx.x;
  const int tx = t & 31, ty = t >> 5;
  const int rx = t & 63, cy = t >> 6;
  const long r0 = (long)blockIdx.y * 64, c0 = (long)blockIdx.x * 32;
#pragma unroll
  for (int i = 0; i < 8; ++i)
    tile[ty + i * 8][tx] = in[(r0 + ty + i * 8) * C + c0 + tx];
  __syncthreads();
#pragma unroll
  for (int i = 0; i < 8; ++i) {
    const int c = (int)c0 + i * 4 + cy;
    const long v = ((long)(c >> 4) << 5) + off + (c & 15);
    out[v * R + r0 + rx] = f2bf(tile[rx][i * 4 + cy]);
  }
}

// ------------- RoPE cos/sin table: tbl[0..65535]=cos(s,d0), [65536..]=sin -------------
__global__ __launch_bounds__(256) void trig_kernel(float* __restrict__ tbl) {
  const int i = blockIdx.x * 256 + threadIdx.x;   // 65536 = 2048 s x 32 d0
  const int s = i >> 5, d0 = i & 31;
  const float inv = exp2f((float)d0 * (-13.287712379549449f / 32.f));
  float sn, cs;
  sincosf((float)s * inv, &sn, &cs);
  tbl[i] = cs;
  tbl[65536 + i] = sn;
}

// ------------- local-causal flash attention, window 256, hd=64, H=16 -------------
__global__ __launch_bounds__(64, 4) void attn_kernel(const u16* __restrict__ qr,
                                                     const u16* __restrict__ kr,
                                                     const u16* __restrict__ vt,
                                                     u16* __restrict__ o) {
  __shared__ __attribute__((aligned(16))) u16 Pl[16][40];
  int wg = blockIdx.x;
  wg = (wg & 7) * 512 + (wg >> 3);
  const int qt = wg & 127;
  const int bh = wg >> 7;
  const int qs = qt * 16;
  const int l = threadIdx.x;
  const int lr = l & 15, lg = l >> 4;
  const long bho = (long)(bh >> 4) * 2048 * 1024 + (long)(bh & 15) * 64;
  const long vtb = (long)bh * 64 * 2048;

  const u16* qp = qr + bho + (long)(qs + lr) * 1024 + lg * 8;
  const bf16x8 aq0 = *(const bf16x8*)qp;
  const bf16x8 aq1 = *(const bf16x8*)(qp + 32);

  f32x4 oacc[4];
#pragma unroll
  for (int nt = 0; nt < 4; ++nt) { oacc[nt][0] = 0.f; oacc[nt][1] = 0.f; oacc[nt][2] = 0.f; oacc[nt][3] = 0.f; }
  float m_[4], ls[4];
#pragma unroll
  for (int r = 0; r < 4; ++r) { m_[r] = -1e30f; ls[r] = 0.f; }

  for (int ch = 0; ch < 9; ++ch) {
    const int j0 = qs - 256 + ch * 32;
    if (j0 + 32 <= 0) continue;

    const int jc0u = j0 + lr;
    const int jc1u = j0 + 16 + lr;
    const int jc0 = min(max(jc0u, 0), 2047);
    const int jc1 = min(max(jc1u, 0), 2047);
    const u16* kp0 = kr + bho + (long)jc0 * 1024 + lg * 8;
    const u16* kp1 = kr + bho + (long)jc1 * 1024 + lg * 8;
    const bf16x8 b00 = *(const bf16x8*)kp0;
    const bf16x8 b01 = *(const bf16x8*)(kp0 + 32);
    const bf16x8 b10 = *(const bf16x8*)kp1;
    const bf16x8 b11 = *(const bf16x8*)(kp1 + 32);

    f32x4 z; z[0] = 0.f; z[1] = 0.f; z[2] = 0.f; z[3] = 0.f;
    f32x4 s0 = __builtin_amdgcn_mfma_f32_16x16x32_bf16(aq0, b00, z, 0, 0, 0);
    s0 = __builtin_amdgcn_mfma_f32_16x16x32_bf16(aq1, b01, s0, 0, 0, 0);
    f32x4 s1 = __builtin_amdgcn_mfma_f32_16x16x32_bf16(aq0, b10, z, 0, 0, 0);
    s1 = __builtin_amdgcn_mfma_f32_16x16x32_bf16(aq1, b11, s1, 0, 0, 0);

    float p0[4], p1[4], al[4];
#pragma unroll
    for (int r = 0; r < 4; ++r) {
      const int qg = qs + lg * 4 + r;
      const bool v0 = (jc0u >= 0) & (jc0u <= qg) & (qg - jc0u <= 256);
      const bool v1 = (jc1u >= 0) & (jc1u <= qg) & (qg - jc1u <= 256);
      const float t0 = v0 ? s0[r] : -1e30f;
      const float t1 = v1 ? s1[r] : -1e30f;
      float mx = fmaxf(t0, t1);
      mx = fmaxf(mx, __shfl_xor(mx, 1));
      mx = fmaxf(mx, __shfl_xor(mx, 2));
      mx = fmaxf(mx, __shfl_xor(mx, 4));
      mx = fmaxf(mx, __shfl_xor(mx, 8));
      const float mn = fmaxf(m_[r], mx);
      if (mn < -1e29f) {
        al[r] = 1.f; p0[r] = 0.f; p1[r] = 0.f;
      } else {
        al[r] = __expf(m_[r] - mn);
        p0[r] = (t0 < -1e29f) ? 0.f : __expf(t0 - mn);
        p1[r] = (t1 < -1e29f) ? 0.f : __expf(t1 - mn);
      }
      m_[r] = mn;
      float rs = p0[r] + p1[r];
      rs += __shfl_xor(rs, 1);
      rs += __shfl_xor(rs, 2);
      rs += __shfl_xor(rs, 4);
      rs += __shfl_xor(rs, 8);
      ls[r] = ls[r] * al[r] + rs;
    }
#pragma unroll
    for (int r = 0; r < 4; ++r) {
      Pl[lg * 4 + r][lr] = f2bf(p0[r]);
      Pl[lg * 4 + r][lr + 16] = f2bf(p1[r]);
    }
    asm volatile("s_waitcnt lgkmcnt(0)" ::: "memory");
    const bf16x8 pa = *(const bf16x8*)(&Pl[lr][lg * 8]);

    const int jb = min(max(j0 + lg * 8, 0), 2040);
    const u16* vp = vt + vtb + (long)lr * 2048 + jb;
#pragma unroll
    for (int nt = 0; nt < 4; ++nt) {
      const bf16x8 bv = *(const bf16x8*)(vp + (long)(nt * 16) * 2048);
      f32x4 oa = oacc[nt];
#pragma unroll
      for (int r = 0; r < 4; ++r) oa[r] *= al[r];
      oacc[nt] = __builtin_amdgcn_mfma_f32_16x16x32_bf16(pa, bv, oa, 0, 0, 0);
    }
  }
#pragma unroll
  for (int nt = 0; nt < 4; ++nt)
#pragma unroll
    for (int r = 0; r < 4; ++r) {
      const long qg = qs + lg * 4 + r;
      o[bho + qg * 1024 + nt * 16 + lr] = f2bf(oacc[nt][r] / ls[r]);
    }
}

// ========== 256x256 8-phase GEMM, BK=64, A triple-buffered (160 KiB LDS) ==========
// Pipelined: 1 barrier/phase; A-frag reads issued one phase ahead (aA/aB reg dbuf);
// B frags read pre-tile. Block mapping: XCD-contiguous chunks + GROUP_M=8.
// EPI 0: f32 split-K partials -> (z<2?Cf0:Cf1)+(z&1)*M*N
// EPI 6: qkv fused rope epilogue (Cb=qr, P1=kr, P2=vt[bh][64][2048], tbl=cos/sin)
// EPI 7: fused gate/up (interleaved wguT, virtual N=8192) -> bf16 [M][4096]
__device__ __forceinline__ void stage_half(u16* lds, int ldsbase,
                                           const u16* gp, int ld, int col,
                                           int tid, int w) {
  const int r0 = tid >> 3;
  const int sw = ((tid & 7) ^ (r0 & 7)) << 3;
  gload_lds16(gp + (long)r0 * ld + col + sw, lds + ldsbase + w * 512);
  gload_lds16(gp + (long)(r0 + 64) * ld + col + sw, lds + ldsbase + 4096 + w * 512);
}

template <int EPI>
__global__ __launch_bounds__(512, 2) void gemm8p(const u16* __restrict__ A,
                                                 const u16* __restrict__ BT,
                                                 u16* __restrict__ Cb,
                                                 const float* __restrict__ bias,
                                                 float* __restrict__ Cf0,
                                                 float* __restrict__ Cf1,
                                                 u16* __restrict__ P1,
                                                 u16* __restrict__ P2,
                                                 const float* __restrict__ tbl,
                                                 int M, int N, int Kfull, int Kl) {
  __shared__ __attribute__((aligned(16))) u16 lds[81920];   // 160 KiB
  const int tid = threadIdx.x;
  const int w = tid >> 6, l = tid & 63;
  const int lr = l & 15, lg = l >> 4;
  const int l7 = l & 7;
  const int wr = w >> 2, wc = w & 3;
  const int nbx = N >> 8, nby = M >> 8;
  int wg = blockIdx.x;
  { const int cpx = gridDim.x >> 3; wg = (wg & 7) * cpx + (wg >> 3); }
  const int z = wg / (nbx * nby);
  const int rem = wg % (nbx * nby);
  const int rr = rem % (8 * nbx);
  const long m0 = (long)((rem / (8 * nbx)) * 8 + (rr & 7)) * 256;
  const long n0 = (long)(rr >> 3) * 256;
  const long koff = (long)z * Kl;
  const int NT = Kl >> 6;

  f32x4 acc[8][4];
#pragma unroll
  for (int i = 0; i < 8; ++i)
#pragma unroll
    for (int j = 0; j < 4; ++j) { acc[i][j][0] = 0.f; acc[i][j][1] = 0.f; acc[i][j][2] = 0.f; acc[i][j][3] = 0.f; }

  const u16* Alo = A + m0 * Kfull + koff;
  const u16* Ahi = A + (m0 + 128) * Kfull + koff;
  const u16* Blo = BT + n0 * Kfull + koff;
  const u16* Bhi = BT + (n0 + 128) * Kfull + koff;

  // prologue: A(0), B(0), A(1), B(1) — oldest-first so vmcnt(8) releases A0/B0
  stage_half(lds, 0, Alo, Kfull, 0, tid, w);
  stage_half(lds, 8192, Ahi, Kfull, 0, tid, w);
  stage_half(lds, 49152, Blo, Kfull, 0, tid, w);
  stage_half(lds, 57344, Bhi, Kfull, 0, tid, w);
  stage_half(lds, 16384, Alo, Kfull, 64, tid, w);
  stage_half(lds, 24576, Ahi, Kfull, 64, tid, w);
  stage_half(lds, 65536, Blo, Kfull, 64, tid, w);
  stage_half(lds, 73728, Bhi, Kfull, 64, tid, w);
  asm volatile("s_waitcnt vmcnt(8)" ::: "memory");
  __builtin_amdgcn_s_barrier();

  for (int t = 0; t < NT; ++t) {
    const int abuf = t % 3;
    int sA = abuf + 2; if (sA >= 3) sA -= 3;     // (t+2)%3
    const int p = t & 1;
    const int baA = abuf * 16384 + wr * 8192;
    const int bB = 49152 + p * 16384;
    bf16x8 aA[2][2], aB[2][2], b[4][2];
    // pre-tile reads: phase-0 A rows + all B
#pragma unroll
    for (int m2 = 0; m2 < 2; ++m2)
#pragma unroll
      for (int kh = 0; kh < 2; ++kh)
        aA[m2][kh] = *(const bf16x8*)(lds + baA + (m2 * 16 + lr) * 64 + (((kh * 4 + lg) ^ l7) << 3));
#pragma unroll
    for (int fn = 0; fn < 4; ++fn) {
      const int rb = wc * 64 + fn * 16 + lr;
#pragma unroll
      for (int kh = 0; kh < 2; ++kh)
        b[fn][kh] = *(const bf16x8*)(lds + bB + (rb >> 7) * 8192 + (rb & 127) * 64 + (((kh * 4 + lg) ^ l7) << 3));
    }
#pragma unroll
    for (int q = 0; q < 4; ++q) {
      // stage one half-tile of t+2 (A -> 3rd buffer; B -> same-parity buffer)
      if (t + 2 < NT) {
        if (q == 0) stage_half(lds, sA * 16384, Alo, Kfull, (t + 2) * 64, tid, w);
        if (q == 1) stage_half(lds, sA * 16384 + 8192, Ahi, Kfull, (t + 2) * 64, tid, w);
        if (q == 2) stage_half(lds, bB, Blo, Kfull, (t + 2) * 64, tid, w);
        if (q == 3) stage_half(lds, bB + 8192, Bhi, Kfull, (t + 2) * 64, tid, w);
      }
      __builtin_amdgcn_s_setprio(1);
#pragma unroll
      for (int m2 = 0; m2 < 2; ++m2)
#pragma unroll
        for (int fn = 0; fn < 4; ++fn)
#pragma unroll
          for (int kh = 0; kh < 2; ++kh)
            acc[q * 2 + m2][fn] = __builtin_amdgcn_mfma_f32_16x16x32_bf16(
                (q & 1) ? aB[m2][kh] : aA[m2][kh], b[fn][kh], acc[q * 2 + m2][fn], 0, 0, 0);
      __builtin_amdgcn_s_setprio(0);
      if (q < 3) {
        // prefetch next phase's A rows (buffer abuf is stable all tile)
#pragma unroll
        for (int m2 = 0; m2 < 2; ++m2)
#pragma unroll
          for (int kh = 0; kh < 2; ++kh) {
            const int rowA = ((q + 1) * 2 + m2) * 16 + lr;
            const bf16x8 v = *(const bf16x8*)(lds + baA + rowA * 64 + (((kh * 4 + lg) ^ l7) << 3));
            if (q & 1) aA[m2][kh] = v; else aB[m2][kh] = v;
          }
      }
      if (q == 3) {
        if (t + 2 < NT) { asm volatile("s_waitcnt vmcnt(8)" ::: "memory"); }
        else            { asm volatile("s_waitcnt vmcnt(0)" ::: "memory"); }
      }
      __builtin_amdgcn_s_barrier();
    }
  }

  if constexpr (EPI == 6) {
    const int regn = (int)((n0 + wc * 64) >> 10);   // 0=Q, 1=K, else V
    if (regn < 2) {
      const float scale = (regn == 0) ? 0.125f : 1.f;
      u16* dst = (regn == 0) ? Cb : P1;
      const int cbase = (int)(n0 & 1023) + wc * 64 + lr;
#pragma unroll
      for (int fm = 0; fm < 8; ++fm) {
        const long mr = m0 + wr * 128 + fm * 16 + lg * 4;
#pragma unroll
        for (int fn = 0; fn < 2; ++fn) {
          const int c1 = cbase + fn * 16;
          const int d0 = fn * 16 + lr;
#pragma unroll
          for (int r = 0; r < 4; ++r) {
            const long row = mr + r;
            const int s = (int)(row & 2047);
            const float cs = tbl[(s << 5) + d0];
            const float sn = tbl[65536 + (s << 5) + d0];
            const float x1v = acc[fm][fn][r], x2v = acc[fm][fn + 2][r];
            dst[row * 1024 + c1] = f2bf((x1v * cs - x2v * sn) * scale);
            dst[row * 1024 + c1 + 32] = f2bf((x2v * cs + x1v * sn) * scale);
          }
        }
      }
    } else {
#pragma unroll
      for (int fm = 0; fm < 8; ++fm) {
        const long mr = m0 + wr * 128 + fm * 16 + lg * 4;
        const int bb = (int)(mr >> 11);
        const int s = (int)(mr & 2047);
#pragma unroll
        for (int fn = 0; fn < 4; ++fn) {
          const int ncv = (int)(n0 - 2048) + wc * 64 + fn * 16 + lr;
          const int h = ncv >> 6, d = ncv & 63;
          u16 pk[4];
#pragma unroll
          for (int r = 0; r < 4; ++r) pk[r] = f2bf(acc[fm][fn][r]);
          *(u64*)(P2 + (long)(bb * 16 + h) * 131072 + (long)d * 2048 + s) = *(u64*)pk;
        }
      }
    }
    return;
  }

  if constexpr (EPI == 7) {
    const int rcb = (int)((n0 + wc * 64) >> 1);
#pragma unroll
    for (int fm = 0; fm < 8; ++fm) {
      const long mr = m0 + wr * 128 + fm * 16 + lg * 4;
#pragma unroll
      for (int fp = 0; fp < 2; ++fp) {
        const int rc = rcb + fp * 16 + lr;
        const float bg = bias[rc];
        const float bu = tbl[rc];
#pragma unroll
        for (int r = 0; r < 4; ++r) {
          const float g = acc[fm][2 * fp][r] + bg;
          const float u = acc[fm][2 * fp + 1][r] + bu;
          const float sg = 1.f / (1.f + __expf(-u));
          Cb[(mr + r) * 4096 + rc] = f2bf(g * u * sg);
        }
      }
    }
    return;
  }

  float* Cf = (z < 2 ? Cf0 : Cf1) + (long)(z & 1) * M * N;
#pragma unroll
  for (int fm = 0; fm < 8; ++fm) {
    const long mr = m0 + wr * 128 + fm * 16 + lg * 4;
#pragma unroll
    for (int fn = 0; fn < 4; ++fn) {
      const long nc = n0 + wc * 64 + fn * 16 + lr;
#pragma unroll
      for (int r = 0; r < 4; ++r)
        Cf[(mr + r) * N + nc] = acc[fm][fn][r];
    }
  }
}

// ------ combine 4 partials + residual, then LayerNorm -> x1 (f32) and y (bf16) ------
__global__ __launch_bounds__(256) void combine_ln(const float* __restrict__ p0,
                                                  const float* __restrict__ p1,
                                                  const float* __restrict__ x,
                                                  const float* __restrict__ g,
                                                  const float* __restrict__ beta,
                                                  float* __restrict__ x1,
                                                  u16* __restrict__ y) {
  __shared__ float red[8];
  const long MN = (long)4096 * 1024;
  const int row = blockIdx.x;
  const int t = threadIdx.x;
  const long base = (long)row * 1024 + t * 4;
  const float4 a = *(const float4*)(p0 + base);
  const float4 b = *(const float4*)(p0 + MN + base);
  const float4 c = *(const float4*)(p1 + base);
  const float4 d = *(const float4*)(p1 + MN + base);
  const float4 r = *(const float4*)(x + base);
  float v[4] = {a.x + b.x + c.x + d.x + r.x, a.y + b.y + c.y + d.y + r.y,
                a.z + b.z + c.z + d.z + r.z, a.w + b.w + c.w + d.w + r.w};
  *(float4*)(x1 + base) = *(float4*)v;
  float s = v[0] + v[1] + v[2] + v[3];
  float sq = v[0] * v[0] + v[1] * v[1] + v[2] * v[2] + v[3] * v[3];
#pragma unroll
  for (int dd = 1; dd < 64; dd <<= 1) {
    s += __shfl_xor(s, dd);
    sq += __shfl_xor(sq, dd);
  }
  if ((t & 63) == 0) { red[t >> 6] = s; red[4 + (t >> 6)] = sq; }
  __syncthreads();
  s = red[0] + red[1] + red[2] + red[3];
  sq = red[4] + red[5] + red[6] + red[7];
  const float mean = s * (1.f / 1024.f);
  const float var = sq * (1.f / 1024.f) - mean * mean;
  const float inv = rsqrtf(var + 1e-5f);
  u16 ov[4];
#pragma unroll
  for (int e = 0; e < 4; ++e)
    ov[e] = f2bf((v[e] - mean) * inv * g[t * 4 + e] + beta[t * 4 + e]);
  *(u64*)(y + base) = *(u64*)ov;
}

// ------ combine 4 partials + bias + residual -> out (f32) ------
__global__ __launch_bounds__(256) void combine4(const float* __restrict__ p0,
                                                const float* __restrict__ p1,
                                                const float* __restrict__ res,
                                                const float* __restrict__ bias,
                                                float* __restrict__ out) {
  const long MN = (long)4096 * 1024;
  const long i = ((long)blockIdx.x * 256 + threadIdx.x) * 4;
  const float4 a = *(const float4*)(p0 + i);
  const float4 b = *(const float4*)(p0 + MN + i);
  const float4 c = *(const float4*)(p1 + i);
  const float4 d = *(const float4*)(p1 + MN + i);
  const float4 r = *(const float4*)(res + i);
  const float4 bb = *(const float4*)(bias + (int)(i & 1023));
  float4 o;
  o.x = a.x + b.x + c.x + d.x + r.x + bb.x;
  o.y = a.y + b.y + c.y + d.y + r.y + bb.y;
  o.z = a.z + b.z + c.z + d.z + r.z + bb.z;
  o.w = a.w + b.w + c.w + d.w + r.w + bb.w;
  *(float4*)(out + i) = o;
}

extern "C" void kernel_launch(void* const* d_in, const int* in_sizes, int n_in,
                              void* d_out, int out_size, void* d_ws, size_t ws_size,
                              hipStream_t stream) {
  (void)in_sizes; (void)n_in; (void)out_size; (void)ws_size;
  const float* x      = (const float*)d_in[0];
  const float* w_qkv  = (const float*)d_in[1];
  const float* w_out  = (const float*)d_in[2];
  const float* g1     = (const float*)d_in[3];
  const float* b1     = (const float*)d_in[4];
  const float* g2     = (const float*)d_in[5];
  const float* b2     = (const float*)d_in[6];
  const float* w_gate = (const float*)d_in[7];
  const float* b_gate = (const float*)d_in[8];
  const float* w_up   = (const float*)d_in[9];
  const float* b_up   = (const float*)d_in[10];
  const float* w_down = (const float*)d_in[11];
  const float* b_down = (const float*)d_in[12];
  float* out = (float*)d_out;

  // Workspace layout (MB), liveness-checked (same as R9):
  //  0-8 wdownT | 8-16 y | 16-22 wqkvT | 22-24 woutT | 24-40 wguT
  //  40-48 qr | 48-56 kr | 56-64 vt | 64-64.5 trig (dead after qkv) | 64-72 o_
  //  out-proj partials: 72-104 + 104-136, dead after combine_ln
  //  x1: 56-72 (vt/o_ dead) | gated: 104-136 (part dead)
  //  down partials: pd0 16-48 (wqkvT/woutT/wguT/qr dead by then), pd1 72-104
  const size_t MB = 1u << 20;
  char* ws = (char*)d_ws;
  u16*   wdownT = (u16*)(ws + 0 * MB);
  u16*   y      = (u16*)(ws + 8 * MB);
  u16*   wqkvT  = (u16*)(ws + 16 * MB);
  u16*   woutT  = (u16*)(ws + 22 * MB);
  u16*   wguT   = (u16*)(ws + 24 * MB);     // [8192][1024] interleaved gate/up
  u16*   qr_    = (u16*)(ws + 40 * MB);
  u16*   kr_    = (u16*)(ws + 48 * MB);
  u16*   vt     = (u16*)(ws + 56 * MB);
  float* trig   = (float*)(ws + 64 * MB);
  u16*   o_     = (u16*)(ws + 64 * MB);     // overwrites trig after qkv done
  float* part0  = (float*)(ws + 72 * MB);
  float* part1  = (float*)(ws + 104 * MB);
  float* x1     = (float*)(ws + 56 * MB);
  u16*   gated  = (u16*)(ws + 104 * MB);
  float* pd0    = (float*)(ws + 16 * MB);
  float* pd1    = (float*)(ws + 72 * MB);

  const dim3 blk(256);
  transpose_bf16<<<dim3(3072 / 32, 1024 / 64), blk, 0, stream>>>(w_qkv, wqkvT, 1024, 3072);
  transpose_bf16<<<dim3(1024 / 32, 1024 / 64), blk, 0, stream>>>(w_out, woutT, 1024, 1024);
  transpose_ilv<<<dim3(4096 / 32, 1024 / 64), blk, 0, stream>>>(w_gate, wguT, 1024, 4096, 0);
  transpose_ilv<<<dim3(4096 / 32, 1024 / 64), blk, 0, stream>>>(w_up, wguT, 1024, 4096, 16);
  transpose_bf16<<<dim3(1024 / 32, 4096 / 64), blk, 0, stream>>>(w_down, wdownT, 4096, 1024);
  trig_kernel<<<256, blk, 0, stream>>>(trig);

  // LN1: x -> y
  ln_kernel<<<4096, blk, 0, stream>>>(x, g1, b1, y);
  // QKV projection + fused RoPE/V-transpose epilogue -> qr, kr, vt
  gemm8p<6><<<dim3((3072 / 256) * (4096 / 256)), dim3(512), 0, stream>>>(
      y, wqkvT, qr_, nullptr, nullptr, nullptr, kr_, vt, trig,
      4096, 3072, 1024, 1024);
  // local-causal attention -> o_
  attn_kernel<<<4096, dim3(64), 0, stream>>>(qr_, kr_, vt, o_);
  // out-proj, split-K=4 (Kl=256) -> part0/part1; combine + residual + LN2 -> x1, y
  gemm8p<0><<<dim3(4 * 16 * 4), dim3(512), 0, stream>>>(
      o_, woutT, nullptr, nullptr, part0, part1, nullptr, nullptr, nullptr,
      4096, 1024, 1024, 256);
  combine_ln<<<4096, blk, 0, stream>>>(part0, part1, x, g2, b2, x1, y);
  // fused gate/up dual GEMM (virtual N=8192, interleaved) -> gated bf16 [4096][4096]
  gemm8p<7><<<dim3((8192 / 256) * (4096 / 256)), dim3(512), 0, stream>>>(
      y, wguT, gated, b_gate, nullptr, nullptr, nullptr, nullptr, b_up,
      4096, 8192, 1024, 1024);
  // down-proj, split-K=4 (Kl=1024) -> pd0/pd1; combine + bias + residual -> out
  gemm8p<0><<<dim3(4 * 16 * 4), dim3(512), 0, stream>>>(
      gated, wdownT, nullptr, nullptr, pd0, pd1, nullptr, nullptr, nullptr,
      4096, 1024, 4096, 1024);
  combine4<<<4096, blk, 0, stream>>>(pd0, pd1, x1, b_down, out);
}

// Round 13
// 251.616 us; speedup vs baseline: 1.3056x; 1.0569x over previous
//
#include <hip/hip_runtime.h>

typedef unsigned short u16;
typedef unsigned long long u64;
typedef __attribute__((ext_vector_type(8))) short bf16x8;
typedef __attribute__((ext_vector_type(4))) float f32x4;

__device__ inline u16 f2bf(float f) {
  unsigned int u = __float_as_uint(f);
  u += 0x7fffu + ((u >> 16) & 1u);
  return (u16)(u >> 16);
}
__device__ inline float bf2f(u16 h) { return __uint_as_float(((unsigned int)h) << 16); }

__device__ inline void gload_lds16(const void* gp, void* lp) {
  __builtin_amdgcn_global_load_lds(
      (const __attribute__((address_space(1))) unsigned int*)gp,
      (__attribute__((address_space(3))) unsigned int*)lp, 16, 0, 0);
}

// ---------------- LayerNorm: f32 [rows][1024] -> bf16 ----------------
__global__ __launch_bounds__(256) void ln_kernel(const float* __restrict__ x,
                                                 const float* __restrict__ g,
                                                 const float* __restrict__ beta,
                                                 u16* __restrict__ y) {
  __shared__ float red[8];
  const int row = blockIdx.x;
  const int t = threadIdx.x;
  const float4 xv = *(const float4*)(x + (long)row * 1024 + t * 4);
  float s = xv.x + xv.y + xv.z + xv.w;
  float sq = xv.x * xv.x + xv.y * xv.y + xv.z * xv.z + xv.w * xv.w;
#pragma unroll
  for (int d = 1; d < 64; d <<= 1) {
    s += __shfl_xor(s, d);
    sq += __shfl_xor(sq, d);
  }
  if ((t & 63) == 0) { red[t >> 6] = s; red[4 + (t >> 6)] = sq; }
  __syncthreads();
  s = red[0] + red[1] + red[2] + red[3];
  sq = red[4] + red[5] + red[6] + red[7];
  const float mean = s * (1.f / 1024.f);
  const float var = sq * (1.f / 1024.f) - mean * mean;
  const float inv = rsqrtf(var + 1e-5f);
  float xe[4] = {xv.x, xv.y, xv.z, xv.w};
  u16 ov[4];
#pragma unroll
  for (int e = 0; e < 4; ++e)
    ov[e] = f2bf((xe[e] - mean) * inv * g[t * 4 + e] + beta[t * 4 + e]);
  *(u64*)(y + (long)row * 1024 + t * 4) = *(u64*)ov;
}

// ------------- transpose + convert: f32 in[R][C] -> bf16 out[C][R] -------------
__global__ __launch_bounds__(256) void transpose_bf16(const float* __restrict__ in,
                                                      u16* __restrict__ out,
                                                      int R, int C) {
  __shared__ float tile[64][33];
  const int t = threadIdx.x;
  const int tx = t & 31, ty = t >> 5;
  const int rx = t & 63, cy = t >> 6;
  const long r0 = (long)blockIdx.y * 64, c0 = (long)blockIdx.x * 32;
#pragma unroll
  for (int i = 0; i < 8; ++i)
    tile[ty + i * 8][tx] = in[(r0 + ty + i * 8) * C + c0 + tx];
  __syncthreads();
#pragma unroll
  for (int i = 0; i < 8; ++i)
    out[(c0 + i * 4 + cy) * R + r0 + rx] = f2bf(tile[rx][i * 4 + cy]);
}

// ---- interleaved transpose for gate/up: col c -> row (c>>4)*32 + off + (c&15) ----
__global__ __launch_bounds__(256) void transpose_ilv(const float* __restrict__ in,
                                                     u16* __restrict__ out,
                                                     int R, int C, int off) {
  __shared__ float tile[64][33];
  const int t = threadIdx.x;
  const int tx = t & 31, ty = t >> 5;
  const int rx = t & 63, cy = t >> 6;
  const long r0 = (long)blockIdx.y * 64, c0 = (long)blockIdx.x * 32;
#pragma unroll
  for (int i = 0; i < 8; ++i)
    tile[ty + i * 8][tx] = in[(r0 + ty + i * 8) * C + c0 + tx];
  __syncthreads();
#pragma unroll
  for (int i = 0; i < 8; ++i) {
    const int c = (int)c0 + i * 4 + cy;
    const long v = ((long)(c >> 4) << 5) + off + (c & 15);
    out[v * R + r0 + rx] = f2bf(tile[rx][i * 4 + cy]);
  }
}

// ------------- RoPE cos/sin table: tbl[0..65535]=cos(s,d0), [65536..]=sin -------------
__global__ __launch_bounds__(256) void trig_kernel(float* __restrict__ tbl) {
  const int i = blockIdx.x * 256 + threadIdx.x;   // 65536 = 2048 s x 32 d0
  const int s = i >> 5, d0 = i & 31;
  const float inv = exp2f((float)d0 * (-13.287712379549449f / 32.f));
  float sn, cs;
  sincosf((float)s * inv, &sn, &cs);
  tbl[i] = cs;
  tbl[65536 + i] = sn;
}

// ------------- local-causal flash attention, window 256, hd=64, H=16 -------------
__global__ __launch_bounds__(64, 4) void attn_kernel(const u16* __restrict__ qr,
                                                     const u16* __restrict__ kr,
                                                     const u16* __restrict__ vt,
                                                     u16* __restrict__ o) {
  __shared__ __attribute__((aligned(16))) u16 Pl[16][40];
  int wg = blockIdx.x;
  wg = (wg & 7) * 512 + (wg >> 3);
  const int qt = wg & 127;
  const int bh = wg >> 7;
  const int qs = qt * 16;
  const int l = threadIdx.x;
  const int lr = l & 15, lg = l >> 4;
  const long bho = (long)(bh >> 4) * 2048 * 1024 + (long)(bh & 15) * 64;
  const long vtb = (long)bh * 64 * 2048;

  const u16* qp = qr + bho + (long)(qs + lr) * 1024 + lg * 8;
  const bf16x8 aq0 = *(const bf16x8*)qp;
  const bf16x8 aq1 = *(const bf16x8*)(qp + 32);

  f32x4 oacc[4];
#pragma unroll
  for (int nt = 0; nt < 4; ++nt) { oacc[nt][0] = 0.f; oacc[nt][1] = 0.f; oacc[nt][2] = 0.f; oacc[nt][3] = 0.f; }
  float m_[4], ls[4];
#pragma unroll
  for (int r = 0; r < 4; ++r) { m_[r] = -1e30f; ls[r] = 0.f; }

  for (int ch = 0; ch < 9; ++ch) {
    const int j0 = qs - 256 + ch * 32;
    if (j0 + 32 <= 0) continue;

    const int jc0u = j0 + lr;
    const int jc1u = j0 + 16 + lr;
    const int jc0 = min(max(jc0u, 0), 2047);
    const int jc1 = min(max(jc1u, 0), 2047);
    const u16* kp0 = kr + bho + (long)jc0 * 1024 + lg * 8;
    const u16* kp1 = kr + bho + (long)jc1 * 1024 + lg * 8;
    const bf16x8 b00 = *(const bf16x8*)kp0;
    const bf16x8 b01 = *(const bf16x8*)(kp0 + 32);
    const bf16x8 b10 = *(const bf16x8*)kp1;
    const bf16x8 b11 = *(const bf16x8*)(kp1 + 32);

    f32x4 z; z[0] = 0.f; z[1] = 0.f; z[2] = 0.f; z[3] = 0.f;
    f32x4 s0 = __builtin_amdgcn_mfma_f32_16x16x32_bf16(aq0, b00, z, 0, 0, 0);
    s0 = __builtin_amdgcn_mfma_f32_16x16x32_bf16(aq1, b01, s0, 0, 0, 0);
    f32x4 s1 = __builtin_amdgcn_mfma_f32_16x16x32_bf16(aq0, b10, z, 0, 0, 0);
    s1 = __builtin_amdgcn_mfma_f32_16x16x32_bf16(aq1, b11, s1, 0, 0, 0);

    float p0[4], p1[4], al[4];
#pragma unroll
    for (int r = 0; r < 4; ++r) {
      const int qg = qs + lg * 4 + r;
      const bool v0 = (jc0u >= 0) & (jc0u <= qg) & (qg - jc0u <= 256);
      const bool v1 = (jc1u >= 0) & (jc1u <= qg) & (qg - jc1u <= 256);
      const float t0 = v0 ? s0[r] : -1e30f;
      const float t1 = v1 ? s1[r] : -1e30f;
      float mx = fmaxf(t0, t1);
      mx = fmaxf(mx, __shfl_xor(mx, 1));
      mx = fmaxf(mx, __shfl_xor(mx, 2));
      mx = fmaxf(mx, __shfl_xor(mx, 4));
      mx = fmaxf(mx, __shfl_xor(mx, 8));
      const float mn = fmaxf(m_[r], mx);
      if (mn < -1e29f) {
        al[r] = 1.f; p0[r] = 0.f; p1[r] = 0.f;
      } else {
        al[r] = __expf(m_[r] - mn);
        p0[r] = (t0 < -1e29f) ? 0.f : __expf(t0 - mn);
        p1[r] = (t1 < -1e29f) ? 0.f : __expf(t1 - mn);
      }
      m_[r] = mn;
      float rs = p0[r] + p1[r];
      rs += __shfl_xor(rs, 1);
      rs += __shfl_xor(rs, 2);
      rs += __shfl_xor(rs, 4);
      rs += __shfl_xor(rs, 8);
      ls[r] = ls[r] * al[r] + rs;
    }
#pragma unroll
    for (int r = 0; r < 4; ++r) {
      Pl[lg * 4 + r][lr] = f2bf(p0[r]);
      Pl[lg * 4 + r][lr + 16] = f2bf(p1[r]);
    }
    asm volatile("s_waitcnt lgkmcnt(0)" ::: "memory");
    const bf16x8 pa = *(const bf16x8*)(&Pl[lr][lg * 8]);

    const int jb = min(max(j0 + lg * 8, 0), 2040);
    const u16* vp = vt + vtb + (long)lr * 2048 + jb;
#pragma unroll
    for (int nt = 0; nt < 4; ++nt) {
      const bf16x8 bv = *(const bf16x8*)(vp + (long)(nt * 16) * 2048);
      f32x4 oa = oacc[nt];
#pragma unroll
      for (int r = 0; r < 4; ++r) oa[r] *= al[r];
      oacc[nt] = __builtin_amdgcn_mfma_f32_16x16x32_bf16(pa, bv, oa, 0, 0, 0);
    }
  }
#pragma unroll
  for (int nt = 0; nt < 4; ++nt)
#pragma unroll
    for (int r = 0; r < 4; ++r) {
      const long qg = qs + lg * 4 + r;
      o[bho + qg * 1024 + nt * 16 + lr] = f2bf(oacc[nt][r] / ls[r]);
    }
}

// ========== 256x256 8-phase GEMM, BK=64, A triple-buffered (160 KiB LDS) ==========
// Pipelined: 1 barrier/phase; A-frag reads issued one phase ahead (aA/aB reg dbuf);
// B frags read pre-tile. Block mapping: XCD-contiguous chunks + GROUP_M=8.
// EPI 0: bf16 split-K partials -> ((u16*)(z<2?Cf0:Cf1))+(z&1)*M*N
// EPI 6: qkv fused rope epilogue (Cb=qr, P1=kr, P2=vt[bh][64][2048], tbl=cos/sin)
// EPI 7: fused gate/up (interleaved wguT, virtual N=8192) -> bf16 [M][4096]
__device__ __forceinline__ void stage_half(u16* lds, int ldsbase,
                                           const u16* gp, int ld, int col,
                                           int tid, int w) {
  const int r0 = tid >> 3;
  const int sw = ((tid & 7) ^ (r0 & 7)) << 3;
  gload_lds16(gp + (long)r0 * ld + col + sw, lds + ldsbase + w * 512);
  gload_lds16(gp + (long)(r0 + 64) * ld + col + sw, lds + ldsbase + 4096 + w * 512);
}

template <int EPI>
__global__ __launch_bounds__(512, 2) void gemm8p(const u16* __restrict__ A,
                                                 const u16* __restrict__ BT,
                                                 u16* __restrict__ Cb,
                                                 const float* __restrict__ bias,
                                                 float* __restrict__ Cf0,
                                                 float* __restrict__ Cf1,
                                                 u16* __restrict__ P1,
                                                 u16* __restrict__ P2,
                                                 const float* __restrict__ tbl,
                                                 int M, int N, int Kfull, int Kl) {
  __shared__ __attribute__((aligned(16))) u16 lds[81920];   // 160 KiB
  const int tid = threadIdx.x;
  const int w = tid >> 6, l = tid & 63;
  const int lr = l & 15, lg = l >> 4;
  const int l7 = l & 7;
  const int wr = w >> 2, wc = w & 3;
  const int nbx = N >> 8, nby = M >> 8;
  int wg = blockIdx.x;
  { const int cpx = gridDim.x >> 3; wg = (wg & 7) * cpx + (wg >> 3); }
  const int z = wg / (nbx * nby);
  const int rem = wg % (nbx * nby);
  const int rr = rem % (8 * nbx);
  const long m0 = (long)((rem / (8 * nbx)) * 8 + (rr & 7)) * 256;
  const long n0 = (long)(rr >> 3) * 256;
  const long koff = (long)z * Kl;
  const int NT = Kl >> 6;

  f32x4 acc[8][4];
#pragma unroll
  for (int i = 0; i < 8; ++i)
#pragma unroll
    for (int j = 0; j < 4; ++j) { acc[i][j][0] = 0.f; acc[i][j][1] = 0.f; acc[i][j][2] = 0.f; acc[i][j][3] = 0.f; }

  const u16* Alo = A + m0 * Kfull + koff;
  const u16* Ahi = A + (m0 + 128) * Kfull + koff;
  const u16* Blo = BT + n0 * Kfull + koff;
  const u16* Bhi = BT + (n0 + 128) * Kfull + koff;

  // prologue: A(0), B(0), A(1), B(1) — oldest-first so vmcnt(8) releases A0/B0
  stage_half(lds, 0, Alo, Kfull, 0, tid, w);
  stage_half(lds, 8192, Ahi, Kfull, 0, tid, w);
  stage_half(lds, 49152, Blo, Kfull, 0, tid, w);
  stage_half(lds, 57344, Bhi, Kfull, 0, tid, w);
  stage_half(lds, 16384, Alo, Kfull, 64, tid, w);
  stage_half(lds, 24576, Ahi, Kfull, 64, tid, w);
  stage_half(lds, 65536, Blo, Kfull, 64, tid, w);
  stage_half(lds, 73728, Bhi, Kfull, 64, tid, w);
  asm volatile("s_waitcnt vmcnt(8)" ::: "memory");
  __builtin_amdgcn_s_barrier();

  for (int t = 0; t < NT; ++t) {
    const int abuf = t % 3;
    int sA = abuf + 2; if (sA >= 3) sA -= 3;     // (t+2)%3
    const int p = t & 1;
    const int baA = abuf * 16384 + wr * 8192;
    const int bB = 49152 + p * 16384;
    bf16x8 aA[2][2], aB[2][2], b[4][2];
    // pre-tile reads: phase-0 A rows + all B
#pragma unroll
    for (int m2 = 0; m2 < 2; ++m2)
#pragma unroll
      for (int kh = 0; kh < 2; ++kh)
        aA[m2][kh] = *(const bf16x8*)(lds + baA + (m2 * 16 + lr) * 64 + (((kh * 4 + lg) ^ l7) << 3));
#pragma unroll
    for (int fn = 0; fn < 4; ++fn) {
      const int rb = wc * 64 + fn * 16 + lr;
#pragma unroll
      for (int kh = 0; kh < 2; ++kh)
        b[fn][kh] = *(const bf16x8*)(lds + bB + (rb >> 7) * 8192 + (rb & 127) * 64 + (((kh * 4 + lg) ^ l7) << 3));
    }
#pragma unroll
    for (int q = 0; q < 4; ++q) {
      // stage one half-tile of t+2 (A -> 3rd buffer; B -> same-parity buffer)
      if (t + 2 < NT) {
        if (q == 0) stage_half(lds, sA * 16384, Alo, Kfull, (t + 2) * 64, tid, w);
        if (q == 1) stage_half(lds, sA * 16384 + 8192, Ahi, Kfull, (t + 2) * 64, tid, w);
        if (q == 2) stage_half(lds, bB, Blo, Kfull, (t + 2) * 64, tid, w);
        if (q == 3) stage_half(lds, bB + 8192, Bhi, Kfull, (t + 2) * 64, tid, w);
      }
      __builtin_amdgcn_s_setprio(1);
#pragma unroll
      for (int m2 = 0; m2 < 2; ++m2)
#pragma unroll
        for (int fn = 0; fn < 4; ++fn)
#pragma unroll
          for (int kh = 0; kh < 2; ++kh)
            acc[q * 2 + m2][fn] = __builtin_amdgcn_mfma_f32_16x16x32_bf16(
                (q & 1) ? aB[m2][kh] : aA[m2][kh], b[fn][kh], acc[q * 2 + m2][fn], 0, 0, 0);
      __builtin_amdgcn_s_setprio(0);
      if (q < 3) {
        // prefetch next phase's A rows (buffer abuf is stable all tile)
#pragma unroll
        for (int m2 = 0; m2 < 2; ++m2)
#pragma unroll
          for (int kh = 0; kh < 2; ++kh) {
            const int rowA = ((q + 1) * 2 + m2) * 16 + lr;
            const bf16x8 v = *(const bf16x8*)(lds + baA + rowA * 64 + (((kh * 4 + lg) ^ l7) << 3));
            if (q & 1) aA[m2][kh] = v; else aB[m2][kh] = v;
          }
      }
      if (q == 3) {
        if (t + 2 < NT) { asm volatile("s_waitcnt vmcnt(8)" ::: "memory"); }
        else            { asm volatile("s_waitcnt vmcnt(0)" ::: "memory"); }
      }
      __builtin_amdgcn_s_barrier();
    }
  }

  if constexpr (EPI == 6) {
    const int regn = (int)((n0 + wc * 64) >> 10);   // 0=Q, 1=K, else V
    if (regn < 2) {
      const float scale = (regn == 0) ? 0.125f : 1.f;
      u16* dst = (regn == 0) ? Cb : P1;
      const int cbase = (int)(n0 & 1023) + wc * 64 + lr;
#pragma unroll
      for (int fm = 0; fm < 8; ++fm) {
        const long mr = m0 + wr * 128 + fm * 16 + lg * 4;
#pragma unroll
        for (int fn = 0; fn < 2; ++fn) {
          const int c1 = cbase + fn * 16;
          const int d0 = fn * 16 + lr;
#pragma unroll
          for (int r = 0; r < 4; ++r) {
            const long row = mr + r;
            const int s = (int)(row & 2047);
            const float cs = tbl[(s << 5) + d0];
            const float sn = tbl[65536 + (s << 5) + d0];
            const float x1v = acc[fm][fn][r], x2v = acc[fm][fn + 2][r];
            dst[row * 1024 + c1] = f2bf((x1v * cs - x2v * sn) * scale);
            dst[row * 1024 + c1 + 32] = f2bf((x2v * cs + x1v * sn) * scale);
          }
        }
      }
    } else {
#pragma unroll
      for (int fm = 0; fm < 8; ++fm) {
        const long mr = m0 + wr * 128 + fm * 16 + lg * 4;
        const int bb = (int)(mr >> 11);
        const int s = (int)(mr & 2047);
#pragma unroll
        for (int fn = 0; fn < 4; ++fn) {
          const int ncv = (int)(n0 - 2048) + wc * 64 + fn * 16 + lr;
          const int h = ncv >> 6, d = ncv & 63;
          u16 pk[4];
#pragma unroll
          for (int r = 0; r < 4; ++r) pk[r] = f2bf(acc[fm][fn][r]);
          *(u64*)(P2 + (long)(bb * 16 + h) * 131072 + (long)d * 2048 + s) = *(u64*)pk;
        }
      }
    }
    return;
  }

  if constexpr (EPI == 7) {
    const int rcb = (int)((n0 + wc * 64) >> 1);
#pragma unroll
    for (int fm = 0; fm < 8; ++fm) {
      const long mr = m0 + wr * 128 + fm * 16 + lg * 4;
#pragma unroll
      for (int fp = 0; fp < 2; ++fp) {
        const int rc = rcb + fp * 16 + lr;
        const float bg = bias[rc];
        const float bu = tbl[rc];
#pragma unroll
        for (int r = 0; r < 4; ++r) {
          const float g = acc[fm][2 * fp][r] + bg;
          const float u = acc[fm][2 * fp + 1][r] + bu;
          const float sg = 1.f / (1.f + __expf(-u));
          Cb[(mr + r) * 4096 + rc] = f2bf(g * u * sg);
        }
      }
    }
    return;
  }

  // EPI 0: bf16 split-K partials
  u16* Pb = (u16*)(z < 2 ? Cf0 : Cf1) + (long)(z & 1) * M * N;
#pragma unroll
  for (int fm = 0; fm < 8; ++fm) {
    const long mr = m0 + wr * 128 + fm * 16 + lg * 4;
#pragma unroll
    for (int fn = 0; fn < 4; ++fn) {
      const long nc = n0 + wc * 64 + fn * 16 + lr;
#pragma unroll
      for (int r = 0; r < 4; ++r)
        Pb[(mr + r) * N + nc] = f2bf(acc[fm][fn][r]);
    }
  }
}

// ------ combine 4 bf16 partials + residual x, then LayerNorm -> x1 (bf16) and y (bf16) ------
__global__ __launch_bounds__(256) void combine_ln(const u16* __restrict__ p0,
                                                  const u16* __restrict__ p1,
                                                  const float* __restrict__ x,
                                                  const float* __restrict__ g,
                                                  const float* __restrict__ beta,
                                                  u16* __restrict__ x1,
                                                  u16* __restrict__ y) {
  __shared__ float red[8];
  const long MN = (long)4096 * 1024;
  const int row = blockIdx.x;
  const int t = threadIdx.x;
  const long base = (long)row * 1024 + t * 4;
  const u64 a = *(const u64*)(p0 + base);
  const u64 b = *(const u64*)(p0 + MN + base);
  const u64 c = *(const u64*)(p1 + base);
  const u64 d = *(const u64*)(p1 + MN + base);
  const float4 r = *(const float4*)(x + base);
  float v[4];
#pragma unroll
  for (int e = 0; e < 4; ++e)
    v[e] = bf2f((u16)(a >> (16 * e))) + bf2f((u16)(b >> (16 * e))) +
           bf2f((u16)(c >> (16 * e))) + bf2f((u16)(d >> (16 * e)));
  v[0] += r.x; v[1] += r.y; v[2] += r.z; v[3] += r.w;
  u16 xv[4];
#pragma unroll
  for (int e = 0; e < 4; ++e) xv[e] = f2bf(v[e]);
  *(u64*)(x1 + base) = *(u64*)xv;
  float s = v[0] + v[1] + v[2] + v[3];
  float sq = v[0] * v[0] + v[1] * v[1] + v[2] * v[2] + v[3] * v[3];
#pragma unroll
  for (int dd = 1; dd < 64; dd <<= 1) {
    s += __shfl_xor(s, dd);
    sq += __shfl_xor(sq, dd);
  }
  if ((t & 63) == 0) { red[t >> 6] = s; red[4 + (t >> 6)] = sq; }
  __syncthreads();
  s = red[0] + red[1] + red[2] + red[3];
  sq = red[4] + red[5] + red[6] + red[7];
  const float mean = s * (1.f / 1024.f);
  const float var = sq * (1.f / 1024.f) - mean * mean;
  const float inv = rsqrtf(var + 1e-5f);
  u16 ov[4];
#pragma unroll
  for (int e = 0; e < 4; ++e)
    ov[e] = f2bf((v[e] - mean) * inv * g[t * 4 + e] + beta[t * 4 + e]);
  *(u64*)(y + base) = *(u64*)ov;
}

// ------ combine 4 bf16 partials + bias + bf16 residual -> out (f32) ------
__global__ __launch_bounds__(256) void combine4(const u16* __restrict__ p0,
                                                const u16* __restrict__ p1,
                                                const u16* __restrict__ res,
                                                const float* __restrict__ bias,
                                                float* __restrict__ out) {
  const long MN = (long)4096 * 1024;
  const long i = ((long)blockIdx.x * 256 + threadIdx.x) * 4;
  const u64 a = *(const u64*)(p0 + i);
  const u64 b = *(const u64*)(p0 + MN + i);
  const u64 c = *(const u64*)(p1 + i);
  const u64 d = *(const u64*)(p1 + MN + i);
  const u64 rr = *(const u64*)(res + i);
  const float4 bb = *(const float4*)(bias + (int)(i & 1023));
  float o[4];
#pragma unroll
  for (int e = 0; e < 4; ++e)
    o[e] = bf2f((u16)(a >> (16 * e))) + bf2f((u16)(b >> (16 * e))) +
           bf2f((u16)(c >> (16 * e))) + bf2f((u16)(d >> (16 * e))) +
           bf2f((u16)(rr >> (16 * e)));
  o[0] += bb.x; o[1] += bb.y; o[2] += bb.z; o[3] += bb.w;
  *(float4*)(out + i) = *(float4*)o;
}

extern "C" void kernel_launch(void* const* d_in, const int* in_sizes, int n_in,
                              void* d_out, int out_size, void* d_ws, size_t ws_size,
                              hipStream_t stream) {
  (void)in_sizes; (void)n_in; (void)out_size; (void)ws_size;
  const float* x      = (const float*)d_in[0];
  const float* w_qkv  = (const float*)d_in[1];
  const float* w_out  = (const float*)d_in[2];
  const float* g1     = (const float*)d_in[3];
  const float* b1     = (const float*)d_in[4];
  const float* g2     = (const float*)d_in[5];
  const float* b2     = (const float*)d_in[6];
  const float* w_gate = (const float*)d_in[7];
  const float* b_gate = (const float*)d_in[8];
  const float* w_up   = (const float*)d_in[9];
  const float* b_up   = (const float*)d_in[10];
  const float* w_down = (const float*)d_in[11];
  const float* b_down = (const float*)d_in[12];
  float* out = (float*)d_out;

  // Workspace layout (MB), liveness-checked:
  //  0-8 wdownT | 8-16 y | 16-22 wqkvT | 22-24 woutT | 24-40 wguT
  //  40-48 qr | 48-56 kr | 56-64 vt | 64-64.5 trig (dead after qkv) | 64-72 o_
  //  out-proj bf16 partials: part0 72-88 (z0,1), part1 88-104 (z2,3) — dead after combine_ln
  //  x1 (bf16 8MB): 56-64 (vt dead after attn)
  //  gated: 104-136 (part dead after combine_ln)
  //  down bf16 partials: pd0 16-32 (wqkvT/woutT/wguT dead), pd1 72-88 (part0 dead)
  const size_t MB = 1u << 20;
  char* ws = (char*)d_ws;
  u16*   wdownT = (u16*)(ws + 0 * MB);
  u16*   y      = (u16*)(ws + 8 * MB);
  u16*   wqkvT  = (u16*)(ws + 16 * MB);
  u16*   woutT  = (u16*)(ws + 22 * MB);
  u16*   wguT   = (u16*)(ws + 24 * MB);     // [8192][1024] interleaved gate/up
  u16*   qr_    = (u16*)(ws + 40 * MB);
  u16*   kr_    = (u16*)(ws + 48 * MB);
  u16*   vt     = (u16*)(ws + 56 * MB);
  float* trig   = (float*)(ws + 64 * MB);
  u16*   o_     = (u16*)(ws + 64 * MB);     // overwrites trig after qkv done
  u16*   part0  = (u16*)(ws + 72 * MB);
  u16*   part1  = (u16*)(ws + 88 * MB);
  u16*   x1     = (u16*)(ws + 56 * MB);     // bf16, vt dead after attention
  u16*   gated  = (u16*)(ws + 104 * MB);
  u16*   pd0    = (u16*)(ws + 16 * MB);
  u16*   pd1    = (u16*)(ws + 72 * MB);

  const dim3 blk(256);
  transpose_bf16<<<dim3(3072 / 32, 1024 / 64), blk, 0, stream>>>(w_qkv, wqkvT, 1024, 3072);
  transpose_bf16<<<dim3(1024 / 32, 1024 / 64), blk, 0, stream>>>(w_out, woutT, 1024, 1024);
  transpose_ilv<<<dim3(4096 / 32, 1024 / 64), blk, 0, stream>>>(w_gate, wguT, 1024, 4096, 0);
  transpose_ilv<<<dim3(4096 / 32, 1024 / 64), blk, 0, stream>>>(w_up, wguT, 1024, 4096, 16);
  transpose_bf16<<<dim3(1024 / 32, 4096 / 64), blk, 0, stream>>>(w_down, wdownT, 4096, 1024);
  trig_kernel<<<256, blk, 0, stream>>>(trig);

  // LN1: x -> y
  ln_kernel<<<4096, blk, 0, stream>>>(x, g1, b1, y);
  // QKV projection + fused RoPE/V-transpose epilogue -> qr, kr, vt
  gemm8p<6><<<dim3((3072 / 256) * (4096 / 256)), dim3(512), 0, stream>>>(
      y, wqkvT, qr_, nullptr, nullptr, nullptr, kr_, vt, trig,
      4096, 3072, 1024, 1024);
  // local-causal attention -> o_
  attn_kernel<<<4096, dim3(64), 0, stream>>>(qr_, kr_, vt, o_);
  // out-proj, split-K=4 (Kl=256) -> bf16 partials; combine + residual + LN2 -> x1, y
  gemm8p<0><<<dim3(4 * 16 * 4), dim3(512), 0, stream>>>(
      o_, woutT, nullptr, nullptr, (float*)part0, (float*)part1, nullptr, nullptr, nullptr,
      4096, 1024, 1024, 256);
  combine_ln<<<4096, blk, 0, stream>>>(part0, part1, x, g2, b2, x1, y);
  // fused gate/up dual GEMM (virtual N=8192, interleaved) -> gated bf16 [4096][4096]
  gemm8p<7><<<dim3((8192 / 256) * (4096 / 256)), dim3(512), 0, stream>>>(
      y, wguT, gated, b_gate, nullptr, nullptr, nullptr, nullptr, b_up,
      4096, 8192, 1024, 1024);
  // down-proj, split-K=4 (Kl=1024) -> bf16 partials; combine + bias + residual -> out
  gemm8p<0><<<dim3(4 * 16 * 4), dim3(512), 0, stream>>>(
      gated, wdownT, nullptr, nullptr, (float*)pd0, (float*)pd1, nullptr, nullptr, nullptr,
      4096, 1024, 4096, 1024);
  combine4<<<4096, blk, 0, stream>>>(pd0, pd1, x1, b_down, out);
}

// Round 14
// 237.692 us; speedup vs baseline: 1.3821x; 1.0586x over previous
//
#include <hip/hip_runtime.h>

typedef unsigned short u16;
typedef unsigned long long u64;
typedef __attribute__((ext_vector_type(8))) short bf16x8;
typedef __attribute__((ext_vector_type(4))) float f32x4;

__device__ inline u16 f2bf(float f) {
  unsigned int u = __float_as_uint(f);
  u += 0x7fffu + ((u >> 16) & 1u);
  return (u16)(u >> 16);
}
__device__ inline float bf2f(u16 h) { return __uint_as_float(((unsigned int)h) << 16); }

__device__ inline void gload_lds16(const void* gp, void* lp) {
  __builtin_amdgcn_global_load_lds(
      (const __attribute__((address_space(1))) unsigned int*)gp,
      (__attribute__((address_space(3))) unsigned int*)lp, 16, 0, 0);
}

// ============ fused prep: 5 weight transposes + trig table + LN1 ============
// segments (blocks): [0,1536) qkvT | [1536,2048) outT | [2048,4096) gate-ilv |
// [4096,6144) up-ilv | [6144,8192) downT | [8192,8448) trig | [8448,12544) LN1
__device__ __forceinline__ void tr_seg(const float* __restrict__ in,
                                       u16* __restrict__ out,
                                       int R, int C, int bx, int by, int t,
                                       float (*tile)[33]) {
  const int tx = t & 31, ty = t >> 5;
  const int rx = t & 63, cy = t >> 6;
  const long r0 = (long)by * 64, c0 = (long)bx * 32;
#pragma unroll
  for (int i = 0; i < 8; ++i)
    tile[ty + i * 8][tx] = in[(r0 + ty + i * 8) * C + c0 + tx];
  __syncthreads();
#pragma unroll
  for (int i = 0; i < 8; ++i)
    out[(c0 + i * 4 + cy) * R + r0 + rx] = f2bf(tile[rx][i * 4 + cy]);
}

__device__ __forceinline__ void ilv_seg(const float* __restrict__ in,
                                        u16* __restrict__ out,
                                        int R, int C, int off, int bx, int by, int t,
                                        float (*tile)[33]) {
  const int tx = t & 31, ty = t >> 5;
  const int rx = t & 63, cy = t >> 6;
  const long r0 = (long)by * 64, c0 = (long)bx * 32;
#pragma unroll
  for (int i = 0; i < 8; ++i)
    tile[ty + i * 8][tx] = in[(r0 + ty + i * 8) * C + c0 + tx];
  __syncthreads();
#pragma unroll
  for (int i = 0; i < 8; ++i) {
    const int c = (int)c0 + i * 4 + cy;
    const long v = ((long)(c >> 4) << 5) + off + (c & 15);
    out[v * R + r0 + rx] = f2bf(tile[rx][i * 4 + cy]);
  }
}

__global__ __launch_bounds__(256) void prep_kernel(const float* __restrict__ w_qkv,
                                                   const float* __restrict__ w_out,
                                                   const float* __restrict__ w_gate,
                                                   const float* __restrict__ w_up,
                                                   const float* __restrict__ w_down,
                                                   const float* __restrict__ x,
                                                   const float* __restrict__ g1,
                                                   const float* __restrict__ b1,
                                                   u16* __restrict__ wqkvT,
                                                   u16* __restrict__ woutT,
                                                   u16* __restrict__ wguT,
                                                   u16* __restrict__ wdownT,
                                                   u16* __restrict__ y,
                                                   float* __restrict__ tbl) {
  __shared__ float tile[64][33];
  __shared__ float red[8];
  const int b = blockIdx.x;
  const int t = threadIdx.x;
  if (b < 1536) {
    tr_seg(w_qkv, wqkvT, 1024, 3072, b % 96, b / 96, t, tile);
  } else if (b < 2048) {
    const int bb = b - 1536;
    tr_seg(w_out, woutT, 1024, 1024, bb % 32, bb / 32, t, tile);
  } else if (b < 4096) {
    const int bb = b - 2048;
    ilv_seg(w_gate, wguT, 1024, 4096, 0, bb % 128, bb / 128, t, tile);
  } else if (b < 6144) {
    const int bb = b - 4096;
    ilv_seg(w_up, wguT, 1024, 4096, 16, bb % 128, bb / 128, t, tile);
  } else if (b < 8192) {
    const int bb = b - 6144;
    tr_seg(w_down, wdownT, 4096, 1024, bb % 32, bb / 32, t, tile);
  } else if (b < 8448) {
    const int i = (b - 8192) * 256 + t;    // 65536 = 2048 s x 32 d0
    const int s = i >> 5, d0 = i & 31;
    const float inv = exp2f((float)d0 * (-13.287712379549449f / 32.f));
    float sn, cs;
    sincosf((float)s * inv, &sn, &cs);
    tbl[i] = cs;
    tbl[65536 + i] = sn;
  } else {
    // LN1 row
    const int row = b - 8448;
    const float4 xv = *(const float4*)(x + (long)row * 1024 + t * 4);
    float s = xv.x + xv.y + xv.z + xv.w;
    float sq = xv.x * xv.x + xv.y * xv.y + xv.z * xv.z + xv.w * xv.w;
#pragma unroll
    for (int d = 1; d < 64; d <<= 1) {
      s += __shfl_xor(s, d);
      sq += __shfl_xor(sq, d);
    }
    if ((t & 63) == 0) { red[t >> 6] = s; red[4 + (t >> 6)] = sq; }
    __syncthreads();
    s = red[0] + red[1] + red[2] + red[3];
    sq = red[4] + red[5] + red[6] + red[7];
    const float mean = s * (1.f / 1024.f);
    const float var = sq * (1.f / 1024.f) - mean * mean;
    const float inv = rsqrtf(var + 1e-5f);
    float xe[4] = {xv.x, xv.y, xv.z, xv.w};
    u16 ov[4];
#pragma unroll
    for (int e = 0; e < 4; ++e)
      ov[e] = f2bf((xe[e] - mean) * inv * g1[t * 4 + e] + b1[t * 4 + e]);
    *(u64*)(y + (long)row * 1024 + t * 4) = *(u64*)ov;
  }
}

// ------------- local-causal flash attention, window 256, hd=64, H=16 -------------
__global__ __launch_bounds__(64, 4) void attn_kernel(const u16* __restrict__ qr,
                                                     const u16* __restrict__ kr,
                                                     const u16* __restrict__ vt,
                                                     u16* __restrict__ o) {
  __shared__ __attribute__((aligned(16))) u16 Pl[16][40];
  int wg = blockIdx.x;
  wg = (wg & 7) * 512 + (wg >> 3);
  const int qt = wg & 127;
  const int bh = wg >> 7;
  const int qs = qt * 16;
  const int l = threadIdx.x;
  const int lr = l & 15, lg = l >> 4;
  const long bho = (long)(bh >> 4) * 2048 * 1024 + (long)(bh & 15) * 64;
  const long vtb = (long)bh * 64 * 2048;

  const u16* qp = qr + bho + (long)(qs + lr) * 1024 + lg * 8;
  const bf16x8 aq0 = *(const bf16x8*)qp;
  const bf16x8 aq1 = *(const bf16x8*)(qp + 32);

  f32x4 oacc[4];
#pragma unroll
  for (int nt = 0; nt < 4; ++nt) { oacc[nt][0] = 0.f; oacc[nt][1] = 0.f; oacc[nt][2] = 0.f; oacc[nt][3] = 0.f; }
  float m_[4], ls[4];
#pragma unroll
  for (int r = 0; r < 4; ++r) { m_[r] = -1e30f; ls[r] = 0.f; }

  for (int ch = 0; ch < 9; ++ch) {
    const int j0 = qs - 256 + ch * 32;
    if (j0 + 32 <= 0) continue;

    const int jc0u = j0 + lr;
    const int jc1u = j0 + 16 + lr;
    const int jc0 = min(max(jc0u, 0), 2047);
    const int jc1 = min(max(jc1u, 0), 2047);
    const u16* kp0 = kr + bho + (long)jc0 * 1024 + lg * 8;
    const u16* kp1 = kr + bho + (long)jc1 * 1024 + lg * 8;
    const bf16x8 b00 = *(const bf16x8*)kp0;
    const bf16x8 b01 = *(const bf16x8*)(kp0 + 32);
    const bf16x8 b10 = *(const bf16x8*)kp1;
    const bf16x8 b11 = *(const bf16x8*)(kp1 + 32);

    f32x4 z; z[0] = 0.f; z[1] = 0.f; z[2] = 0.f; z[3] = 0.f;
    f32x4 s0 = __builtin_amdgcn_mfma_f32_16x16x32_bf16(aq0, b00, z, 0, 0, 0);
    s0 = __builtin_amdgcn_mfma_f32_16x16x32_bf16(aq1, b01, s0, 0, 0, 0);
    f32x4 s1 = __builtin_amdgcn_mfma_f32_16x16x32_bf16(aq0, b10, z, 0, 0, 0);
    s1 = __builtin_amdgcn_mfma_f32_16x16x32_bf16(aq1, b11, s1, 0, 0, 0);

    float p0[4], p1[4], al[4];
#pragma unroll
    for (int r = 0; r < 4; ++r) {
      const int qg = qs + lg * 4 + r;
      const bool v0 = (jc0u >= 0) & (jc0u <= qg) & (qg - jc0u <= 256);
      const bool v1 = (jc1u >= 0) & (jc1u <= qg) & (qg - jc1u <= 256);
      const float t0 = v0 ? s0[r] : -1e30f;
      const float t1 = v1 ? s1[r] : -1e30f;
      float mx = fmaxf(t0, t1);
      mx = fmaxf(mx, __shfl_xor(mx, 1));
      mx = fmaxf(mx, __shfl_xor(mx, 2));
      mx = fmaxf(mx, __shfl_xor(mx, 4));
      mx = fmaxf(mx, __shfl_xor(mx, 8));
      const float mn = fmaxf(m_[r], mx);
      if (mn < -1e29f) {
        al[r] = 1.f; p0[r] = 0.f; p1[r] = 0.f;
      } else {
        al[r] = __expf(m_[r] - mn);
        p0[r] = (t0 < -1e29f) ? 0.f : __expf(t0 - mn);
        p1[r] = (t1 < -1e29f) ? 0.f : __expf(t1 - mn);
      }
      m_[r] = mn;
      float rs = p0[r] + p1[r];
      rs += __shfl_xor(rs, 1);
      rs += __shfl_xor(rs, 2);
      rs += __shfl_xor(rs, 4);
      rs += __shfl_xor(rs, 8);
      ls[r] = ls[r] * al[r] + rs;
    }
#pragma unroll
    for (int r = 0; r < 4; ++r) {
      Pl[lg * 4 + r][lr] = f2bf(p0[r]);
      Pl[lg * 4 + r][lr + 16] = f2bf(p1[r]);
    }
    asm volatile("s_waitcnt lgkmcnt(0)" ::: "memory");
    const bf16x8 pa = *(const bf16x8*)(&Pl[lr][lg * 8]);

    const int jb = min(max(j0 + lg * 8, 0), 2040);
    const u16* vp = vt + vtb + (long)lr * 2048 + jb;
#pragma unroll
    for (int nt = 0; nt < 4; ++nt) {
      const bf16x8 bv = *(const bf16x8*)(vp + (long)(nt * 16) * 2048);
      f32x4 oa = oacc[nt];
#pragma unroll
      for (int r = 0; r < 4; ++r) oa[r] *= al[r];
      oacc[nt] = __builtin_amdgcn_mfma_f32_16x16x32_bf16(pa, bv, oa, 0, 0, 0);
    }
  }
#pragma unroll
  for (int nt = 0; nt < 4; ++nt)
#pragma unroll
    for (int r = 0; r < 4; ++r) {
      const long qg = qs + lg * 4 + r;
      o[bho + qg * 1024 + nt * 16 + lr] = f2bf(oacc[nt][r] / ls[r]);
    }
}

// ========== 256x256 8-phase GEMM, BK=64, A triple-buffered (160 KiB LDS) ==========
// Pipelined: 1 barrier/phase; A-frag reads issued one phase ahead (aA/aB reg dbuf);
// B frags read pre-tile. Block mapping: XCD-contiguous chunks + GROUP_M=8.
// EPI 0: bf16 split-K partials -> ((u16*)(z<2?Cf0:Cf1))+(z&1)*M*N
// EPI 6: qkv fused rope epilogue (Cb=qr, P1=kr, P2=vt[bh][64][2048], tbl=cos/sin)
// EPI 7: fused gate/up (interleaved wguT, virtual N=8192) -> bf16 [M][4096]
__device__ __forceinline__ void stage_half(u16* lds, int ldsbase,
                                           const u16* gp, int ld, int col,
                                           int tid, int w) {
  const int r0 = tid >> 3;
  const int sw = ((tid & 7) ^ (r0 & 7)) << 3;
  gload_lds16(gp + (long)r0 * ld + col + sw, lds + ldsbase + w * 512);
  gload_lds16(gp + (long)(r0 + 64) * ld + col + sw, lds + ldsbase + 4096 + w * 512);
}

template <int EPI>
__global__ __launch_bounds__(512, 2) void gemm8p(const u16* __restrict__ A,
                                                 const u16* __restrict__ BT,
                                                 u16* __restrict__ Cb,
                                                 const float* __restrict__ bias,
                                                 float* __restrict__ Cf0,
                                                 float* __restrict__ Cf1,
                                                 u16* __restrict__ P1,
                                                 u16* __restrict__ P2,
                                                 const float* __restrict__ tbl,
                                                 int M, int N, int Kfull, int Kl) {
  __shared__ __attribute__((aligned(16))) u16 lds[81920];   // 160 KiB
  const int tid = threadIdx.x;
  const int w = tid >> 6, l = tid & 63;
  const int lr = l & 15, lg = l >> 4;
  const int l7 = l & 7;
  const int wr = w >> 2, wc = w & 3;
  const int nbx = N >> 8, nby = M >> 8;
  int wg = blockIdx.x;
  { const int cpx = gridDim.x >> 3; wg = (wg & 7) * cpx + (wg >> 3); }
  const int z = wg / (nbx * nby);
  const int rem = wg % (nbx * nby);
  const int rr = rem % (8 * nbx);
  const long m0 = (long)((rem / (8 * nbx)) * 8 + (rr & 7)) * 256;
  const long n0 = (long)(rr >> 3) * 256;
  const long koff = (long)z * Kl;
  const int NT = Kl >> 6;

  f32x4 acc[8][4];
#pragma unroll
  for (int i = 0; i < 8; ++i)
#pragma unroll
    for (int j = 0; j < 4; ++j) { acc[i][j][0] = 0.f; acc[i][j][1] = 0.f; acc[i][j][2] = 0.f; acc[i][j][3] = 0.f; }

  const u16* Alo = A + m0 * Kfull + koff;
  const u16* Ahi = A + (m0 + 128) * Kfull + koff;
  const u16* Blo = BT + n0 * Kfull + koff;
  const u16* Bhi = BT + (n0 + 128) * Kfull + koff;

  // prologue: A(0), B(0), A(1), B(1) — oldest-first so vmcnt(8) releases A0/B0
  stage_half(lds, 0, Alo, Kfull, 0, tid, w);
  stage_half(lds, 8192, Ahi, Kfull, 0, tid, w);
  stage_half(lds, 49152, Blo, Kfull, 0, tid, w);
  stage_half(lds, 57344, Bhi, Kfull, 0, tid, w);
  stage_half(lds, 16384, Alo, Kfull, 64, tid, w);
  stage_half(lds, 24576, Ahi, Kfull, 64, tid, w);
  stage_half(lds, 65536, Blo, Kfull, 64, tid, w);
  stage_half(lds, 73728, Bhi, Kfull, 64, tid, w);
  asm volatile("s_waitcnt vmcnt(8)" ::: "memory");
  __builtin_amdgcn_s_barrier();

  for (int t = 0; t < NT; ++t) {
    const int abuf = t % 3;
    int sA = abuf + 2; if (sA >= 3) sA -= 3;     // (t+2)%3
    const int p = t & 1;
    const int baA = abuf * 16384 + wr * 8192;
    const int bB = 49152 + p * 16384;
    bf16x8 aA[2][2], aB[2][2], b[4][2];
    // pre-tile reads: phase-0 A rows + all B
#pragma unroll
    for (int m2 = 0; m2 < 2; ++m2)
#pragma unroll
      for (int kh = 0; kh < 2; ++kh)
        aA[m2][kh] = *(const bf16x8*)(lds + baA + (m2 * 16 + lr) * 64 + (((kh * 4 + lg) ^ l7) << 3));
#pragma unroll
    for (int fn = 0; fn < 4; ++fn) {
      const int rb = wc * 64 + fn * 16 + lr;
#pragma unroll
      for (int kh = 0; kh < 2; ++kh)
        b[fn][kh] = *(const bf16x8*)(lds + bB + (rb >> 7) * 8192 + (rb & 127) * 64 + (((kh * 4 + lg) ^ l7) << 3));
    }
#pragma unroll
    for (int q = 0; q < 4; ++q) {
      // stage one half-tile of t+2 (A -> 3rd buffer; B -> same-parity buffer)
      if (t + 2 < NT) {
        if (q == 0) stage_half(lds, sA * 16384, Alo, Kfull, (t + 2) * 64, tid, w);
        if (q == 1) stage_half(lds, sA * 16384 + 8192, Ahi, Kfull, (t + 2) * 64, tid, w);
        if (q == 2) stage_half(lds, bB, Blo, Kfull, (t + 2) * 64, tid, w);
        if (q == 3) stage_half(lds, bB + 8192, Bhi, Kfull, (t + 2) * 64, tid, w);
      }
      __builtin_amdgcn_s_setprio(1);
#pragma unroll
      for (int m2 = 0; m2 < 2; ++m2)
#pragma unroll
        for (int fn = 0; fn < 4; ++fn)
#pragma unroll
          for (int kh = 0; kh < 2; ++kh)
            acc[q * 2 + m2][fn] = __builtin_amdgcn_mfma_f32_16x16x32_bf16(
                (q & 1) ? aB[m2][kh] : aA[m2][kh], b[fn][kh], acc[q * 2 + m2][fn], 0, 0, 0);
      __builtin_amdgcn_s_setprio(0);
      if (q < 3) {
        // prefetch next phase's A rows (buffer abuf is stable all tile)
#pragma unroll
        for (int m2 = 0; m2 < 2; ++m2)
#pragma unroll
          for (int kh = 0; kh < 2; ++kh) {
            const int rowA = ((q + 1) * 2 + m2) * 16 + lr;
            const bf16x8 v = *(const bf16x8*)(lds + baA + rowA * 64 + (((kh * 4 + lg) ^ l7) << 3));
            if (q & 1) aA[m2][kh] = v; else aB[m2][kh] = v;
          }
      }
      if (q == 3) {
        if (t + 2 < NT) { asm volatile("s_waitcnt vmcnt(8)" ::: "memory"); }
        else            { asm volatile("s_waitcnt vmcnt(0)" ::: "memory"); }
      }
      __builtin_amdgcn_s_barrier();
    }
  }

  if constexpr (EPI == 6) {
    const int regn = (int)((n0 + wc * 64) >> 10);   // 0=Q, 1=K, else V
    if (regn < 2) {
      const float scale = (regn == 0) ? 0.125f : 1.f;
      u16* dst = (regn == 0) ? Cb : P1;
      const int cbase = (int)(n0 & 1023) + wc * 64 + lr;
#pragma unroll
      for (int fm = 0; fm < 8; ++fm) {
        const long mr = m0 + wr * 128 + fm * 16 + lg * 4;
#pragma unroll
        for (int fn = 0; fn < 2; ++fn) {
          const int c1 = cbase + fn * 16;
          const int d0 = fn * 16 + lr;
#pragma unroll
          for (int r = 0; r < 4; ++r) {
            const long row = mr + r;
            const int s = (int)(row & 2047);
            const float cs = tbl[(s << 5) + d0];
            const float sn = tbl[65536 + (s << 5) + d0];
            const float x1v = acc[fm][fn][r], x2v = acc[fm][fn + 2][r];
            dst[row * 1024 + c1] = f2bf((x1v * cs - x2v * sn) * scale);
            dst[row * 1024 + c1 + 32] = f2bf((x2v * cs + x1v * sn) * scale);
          }
        }
      }
    } else {
#pragma unroll
      for (int fm = 0; fm < 8; ++fm) {
        const long mr = m0 + wr * 128 + fm * 16 + lg * 4;
        const int bb = (int)(mr >> 11);
        const int s = (int)(mr & 2047);
#pragma unroll
        for (int fn = 0; fn < 4; ++fn) {
          const int ncv = (int)(n0 - 2048) + wc * 64 + fn * 16 + lr;
          const int h = ncv >> 6, d = ncv & 63;
          u16 pk[4];
#pragma unroll
          for (int r = 0; r < 4; ++r) pk[r] = f2bf(acc[fm][fn][r]);
          *(u64*)(P2 + (long)(bb * 16 + h) * 131072 + (long)d * 2048 + s) = *(u64*)pk;
        }
      }
    }
    return;
  }

  if constexpr (EPI == 7) {
    const int rcb = (int)((n0 + wc * 64) >> 1);
#pragma unroll
    for (int fm = 0; fm < 8; ++fm) {
      const long mr = m0 + wr * 128 + fm * 16 + lg * 4;
#pragma unroll
      for (int fp = 0; fp < 2; ++fp) {
        const int rc = rcb + fp * 16 + lr;
        const float bg = bias[rc];
        const float bu = tbl[rc];
#pragma unroll
        for (int r = 0; r < 4; ++r) {
          const float g = acc[fm][2 * fp][r] + bg;
          const float u = acc[fm][2 * fp + 1][r] + bu;
          const float sg = 1.f / (1.f + __expf(-u));
          Cb[(mr + r) * 4096 + rc] = f2bf(g * u * sg);
        }
      }
    }
    return;
  }

  // EPI 0: bf16 split-K partials
  u16* Pb = (u16*)(z < 2 ? Cf0 : Cf1) + (long)(z & 1) * M * N;
#pragma unroll
  for (int fm = 0; fm < 8; ++fm) {
    const long mr = m0 + wr * 128 + fm * 16 + lg * 4;
#pragma unroll
    for (int fn = 0; fn < 4; ++fn) {
      const long nc = n0 + wc * 64 + fn * 16 + lr;
#pragma unroll
      for (int r = 0; r < 4; ++r)
        Pb[(mr + r) * N + nc] = f2bf(acc[fm][fn][r]);
    }
  }
}

// ------ combine 4 bf16 partials + residual x, then LayerNorm -> x1 (bf16) and y (bf16) ------
__global__ __launch_bounds__(256) void combine_ln(const u16* __restrict__ p0,
                                                  const u16* __restrict__ p1,
                                                  const float* __restrict__ x,
                                                  const float* __restrict__ g,
                                                  const float* __restrict__ beta,
                                                  u16* __restrict__ x1,
                                                  u16* __restrict__ y) {
  __shared__ float red[8];
  const long MN = (long)4096 * 1024;
  const int row = blockIdx.x;
  const int t = threadIdx.x;
  const long base = (long)row * 1024 + t * 4;
  const u64 a = *(const u64*)(p0 + base);
  const u64 b = *(const u64*)(p0 + MN + base);
  const u64 c = *(const u64*)(p1 + base);
  const u64 d = *(const u64*)(p1 + MN + base);
  const float4 r = *(const float4*)(x + base);
  float v[4];
#pragma unroll
  for (int e = 0; e < 4; ++e)
    v[e] = bf2f((u16)(a >> (16 * e))) + bf2f((u16)(b >> (16 * e))) +
           bf2f((u16)(c >> (16 * e))) + bf2f((u16)(d >> (16 * e)));
  v[0] += r.x; v[1] += r.y; v[2] += r.z; v[3] += r.w;
  u16 xv[4];
#pragma unroll
  for (int e = 0; e < 4; ++e) xv[e] = f2bf(v[e]);
  *(u64*)(x1 + base) = *(u64*)xv;
  float s = v[0] + v[1] + v[2] + v[3];
  float sq = v[0] * v[0] + v[1] * v[1] + v[2] * v[2] + v[3] * v[3];
#pragma unroll
  for (int dd = 1; dd < 64; dd <<= 1) {
    s += __shfl_xor(s, dd);
    sq += __shfl_xor(sq, dd);
  }
  if ((t & 63) == 0) { red[t >> 6] = s; red[4 + (t >> 6)] = sq; }
  __syncthreads();
  s = red[0] + red[1] + red[2] + red[3];
  sq = red[4] + red[5] + red[6] + red[7];
  const float mean = s * (1.f / 1024.f);
  const float var = sq * (1.f / 1024.f) - mean * mean;
  const float inv = rsqrtf(var + 1e-5f);
  u16 ov[4];
#pragma unroll
  for (int e = 0; e < 4; ++e)
    ov[e] = f2bf((v[e] - mean) * inv * g[t * 4 + e] + beta[t * 4 + e]);
  *(u64*)(y + base) = *(u64*)ov;
}

// ------ combine 4 bf16 partials + bias + bf16 residual -> out (f32) ------
__global__ __launch_bounds__(256) void combine4(const u16* __restrict__ p0,
                                                const u16* __restrict__ p1,
                                                const u16* __restrict__ res,
                                                const float* __restrict__ bias,
                                                float* __restrict__ out) {
  const long MN = (long)4096 * 1024;
  const long i = ((long)blockIdx.x * 256 + threadIdx.x) * 4;
  const u64 a = *(const u64*)(p0 + i);
  const u64 b = *(const u64*)(p0 + MN + i);
  const u64 c = *(const u64*)(p1 + i);
  const u64 d = *(const u64*)(p1 + MN + i);
  const u64 rr = *(const u64*)(res + i);
  const float4 bb = *(const float4*)(bias + (int)(i & 1023));
  float o[4];
#pragma unroll
  for (int e = 0; e < 4; ++e)
    o[e] = bf2f((u16)(a >> (16 * e))) + bf2f((u16)(b >> (16 * e))) +
           bf2f((u16)(c >> (16 * e))) + bf2f((u16)(d >> (16 * e))) +
           bf2f((u16)(rr >> (16 * e)));
  o[0] += bb.x; o[1] += bb.y; o[2] += bb.z; o[3] += bb.w;
  *(float4*)(out + i) = *(float4*)o;
}

extern "C" void kernel_launch(void* const* d_in, const int* in_sizes, int n_in,
                              void* d_out, int out_size, void* d_ws, size_t ws_size,
                              hipStream_t stream) {
  (void)in_sizes; (void)n_in; (void)out_size; (void)ws_size;
  const float* x      = (const float*)d_in[0];
  const float* w_qkv  = (const float*)d_in[1];
  const float* w_out  = (const float*)d_in[2];
  const float* g1     = (const float*)d_in[3];
  const float* b1     = (const float*)d_in[4];
  const float* g2     = (const float*)d_in[5];
  const float* b2     = (const float*)d_in[6];
  const float* w_gate = (const float*)d_in[7];
  const float* b_gate = (const float*)d_in[8];
  const float* w_up   = (const float*)d_in[9];
  const float* b_up   = (const float*)d_in[10];
  const float* w_down = (const float*)d_in[11];
  const float* b_down = (const float*)d_in[12];
  float* out = (float*)d_out;

  // Workspace layout (MB), liveness-checked (same as R12):
  //  0-8 wdownT | 8-16 y | 16-22 wqkvT | 22-24 woutT | 24-40 wguT
  //  40-48 qr | 48-56 kr | 56-64 vt | 64-64.5 trig (dead after qkv) | 64-72 o_
  //  out-proj bf16 partials: part0 72-88 (z0,1), part1 88-104 (z2,3)
  //  x1 (bf16 8MB): 56-64 (vt dead after attn)
  //  gated: 104-136 | down partials: pd0 16-32, pd1 72-88
  const size_t MB = 1u << 20;
  char* ws = (char*)d_ws;
  u16*   wdownT = (u16*)(ws + 0 * MB);
  u16*   y      = (u16*)(ws + 8 * MB);
  u16*   wqkvT  = (u16*)(ws + 16 * MB);
  u16*   woutT  = (u16*)(ws + 22 * MB);
  u16*   wguT   = (u16*)(ws + 24 * MB);     // [8192][1024] interleaved gate/up
  u16*   qr_    = (u16*)(ws + 40 * MB);
  u16*   kr_    = (u16*)(ws + 48 * MB);
  u16*   vt     = (u16*)(ws + 56 * MB);
  float* trig   = (float*)(ws + 64 * MB);
  u16*   o_     = (u16*)(ws + 64 * MB);     // overwrites trig after qkv done
  u16*   part0  = (u16*)(ws + 72 * MB);
  u16*   part1  = (u16*)(ws + 88 * MB);
  u16*   x1     = (u16*)(ws + 56 * MB);     // bf16, vt dead after attention
  u16*   gated  = (u16*)(ws + 104 * MB);
  u16*   pd0    = (u16*)(ws + 16 * MB);
  u16*   pd1    = (u16*)(ws + 72 * MB);

  const dim3 blk(256);
  // fused prep: all weight transposes + trig + LN1 in one dispatch
  prep_kernel<<<12544, blk, 0, stream>>>(w_qkv, w_out, w_gate, w_up, w_down,
                                         x, g1, b1,
                                         wqkvT, woutT, wguT, wdownT, y, trig);
  // QKV projection + fused RoPE/V-transpose epilogue -> qr, kr, vt
  gemm8p<6><<<dim3((3072 / 256) * (4096 / 256)), dim3(512), 0, stream>>>(
      y, wqkvT, qr_, nullptr, nullptr, nullptr, kr_, vt, trig,
      4096, 3072, 1024, 1024);
  // local-causal attention -> o_
  attn_kernel<<<4096, dim3(64), 0, stream>>>(qr_, kr_, vt, o_);
  // out-proj, split-K=4 (Kl=256) -> bf16 partials; combine + residual + LN2 -> x1, y
  gemm8p<0><<<dim3(4 * 16 * 4), dim3(512), 0, stream>>>(
      o_, woutT, nullptr, nullptr, (float*)part0, (float*)part1, nullptr, nullptr, nullptr,
      4096, 1024, 1024, 256);
  combine_ln<<<4096, blk, 0, stream>>>(part0, part1, x, g2, b2, x1, y);
  // fused gate/up dual GEMM (virtual N=8192, interleaved) -> gated bf16 [4096][4096]
  gemm8p<7><<<dim3((8192 / 256) * (4096 / 256)), dim3(512), 0, stream>>>(
      y, wguT, gated, b_gate, nullptr, nullptr, nullptr, nullptr, b_up,
      4096, 8192, 1024, 1024);
  // down-proj, split-K=4 (Kl=1024) -> bf16 partials; combine + bias + residual -> out
  gemm8p<0><<<dim3(4 * 16 * 4), dim3(512), 0, stream>>>(
      gated, wdownT, nullptr, nullptr, (float*)pd0, (float*)pd1, nullptr, nullptr, nullptr,
      4096, 1024, 4096, 1024);
  combine4<<<4096, blk, 0, stream>>>(pd0, pd1, x1, b_down, out);
}